// Round 7
// baseline (380.680 us; speedup 1.0000x reference)
//
#include <hip/hip_runtime.h>
#include <math.h>

#define ZB 16
#define NATOMS 192
#define NBAS 40
#define ZA (ZB*NATOMS)       // 3072
#define NKC 32               // K-chunks in contraction

typedef __attribute__((ext_vector_type(4))) float f32x4;
typedef __attribute__((ext_vector_type(8))) short bf16x8;

__device__ __forceinline__ unsigned short f2bf(float x){
    union { float f; unsigned u; } v; v.f = x;
    unsigned r = v.u + 0x7FFFu + ((v.u >> 16) & 1u);
    return (unsigned short)(r >> 16);
}
__device__ __forceinline__ float bf2f(unsigned short u){
    union { unsigned u; float f; } v; v.u = ((unsigned)u) << 16; return v.f;
}
// ssp(x) = softplus(5x)/5 - ln2/5 via hw exp2/log2
__device__ __forceinline__ float sspf(float x){
    float t = 7.2134752f*x;
    float tc = fminf(t, 126.f);
    float e = __builtin_amdgcn_exp2f(tc);
    float l = __builtin_amdgcn_logf(1.f + e);   // log2
    float r = fmaf(l, 0.13862944f, -0.13862944f);
    return (t > 126.f) ? (x - 0.13862944f) : r;
}
__device__ __forceinline__ float spf_act(float x){
    float t = 7.2134752f*x;
    float tc = fminf(t, 126.f);
    float e = __builtin_amdgcn_exp2f(tc);
    float l = __builtin_amdgcn_logf(1.f + e);
    float r = l*0.13862944f;
    return (t > 126.f) ? x : r;
}

// ---------------- prep: w2T[hout*64+hin] = bf16(rW2[hin][hout])
__global__ void k_prep2(const float* __restrict__ rW2, unsigned short* __restrict__ w2T){
    int idx = blockIdx.x*256 + threadIdx.x;     // [0,4096)
    int hout = idx >> 6, hin = idx & 63;
    w2T[idx] = f2bf(rW2[hin*64 + hout]);
}

// ---------------- tmp GEMM bf16 MFMA: Tg[m][s*4096 + j*64 + h] = (f_s[m] @ rWo[h][j][:]) * mask*c
// layer 0 (feat != null): f_s rows computed on the fly from the linear encoders.
__global__ __launch_bounds__(256,3) void k_tmpB(
    const unsigned short* __restrict__ fb, const unsigned short* __restrict__ fc,
    const float* __restrict__ feat,
    const float* __restrict__ Wb, const float* __restrict__ bb,
    const float* __restrict__ Wc, const float* __restrict__ bc,
    const float* __restrict__ mask, const float* __restrict__ rWo,
    unsigned short* __restrict__ Tg)
{
    __shared__ unsigned short sm[18432];   // As[128*72] | Bs[128*72]; Cs overlays all
    __shared__ float msk[128];
    __shared__ float featS[128*8];
    __shared__ float WbS[7*64];
    __shared__ float bbS[64], WcS[64], bcS[64];
    unsigned short* As = sm;
    unsigned short* Bs = sm + 9216;
    unsigned short* Cs = sm;

    int tid = threadIdx.x;
    int m0 = blockIdx.x*128, n0 = blockIdx.y*128, s = blockIdx.z;
    int lane = tid & 63, w = tid >> 6, q = lane >> 4, l15 = lane & 15;
    int wm = w & 1, wn = w >> 1;

    if (feat){
        // stage encoder inputs
        #pragma unroll
        for (int it = 0; it < 4; it++){
            int idx = tid + it*256;            // 1024 floats
            featS[idx] = feat[(size_t)m0*8 + idx];
        }
        for (int i = tid; i < 448; i += 256) WbS[i] = Wb[i];   // 7x64, strided
        if (tid < 64){ bbS[tid] = bb[tid]; WcS[tid] = Wc[tid]; bcS[tid] = bc[tid]; }
        __syncthreads();
        #pragma unroll
        for (int it = 0; it < 32; it++){
            int idx = tid + it*256;            // 8192
            int r = idx >> 6, e = idx & 63;
            float acc;
            if (s == 0){
                acc = bbS[e];
                #pragma unroll
                for (int c = 0; c < 7; c++) acc += featS[r*8+c]*WbS[c*64+e];
            } else {
                acc = bcS[e] + featS[r*8+7]*WcS[e];
            }
            As[r*72 + e] = f2bf(acc);
        }
    } else {
        const unsigned short* f = s ? fc : fb;
        #pragma unroll
        for (int it = 0; it < 4; it++){
            int idx = tid + it*256;            // 1024 uint4
            int r = idx >> 3, c8 = idx & 7;
            *(uint4*)(As + r*72 + c8*8) = *(const uint4*)(f + (size_t)(m0 + r)*64 + c8*8);
        }
    }
    // B-staging: row r -> n = n0+r = j*64+h -> rWo[(h*64+j)*64 + i], fp32->bf16
    #pragma unroll
    for (int it = 0; it < 8; it++){
        int idx = tid + it*256;                // 2048 float4
        int r = idx >> 4, c4 = idx & 15;
        int n = n0 + r;
        int j = n >> 6, h = n & 63;
        float4 v = *(const float4*)(rWo + (size_t)(h*64 + j)*64 + c4*4);
        ushort4 o; o.x = f2bf(v.x); o.y = f2bf(v.y); o.z = f2bf(v.z); o.w = f2bf(v.w);
        *(ushort4*)(Bs + r*72 + c4*4) = o;
    }
    if (tid < 128) msk[tid] = mask[m0 + tid] * 0.07216878364870322f;
    __syncthreads();

    f32x4 acc[16];
    #pragma unroll
    for (int i = 0; i < 16; i++) acc[i] = (f32x4){0.f,0.f,0.f,0.f};
    #pragma unroll
    for (int kc = 0; kc < 2; kc++){
        bf16x8 af[4];
        #pragma unroll
        for (int mt = 0; mt < 4; mt++)
            af[mt] = *(const bf16x8*)(As + (wm*64 + mt*16 + l15)*72 + kc*32 + q*8);
        #pragma unroll
        for (int nt = 0; nt < 4; nt++){
            bf16x8 bf_ = *(const bf16x8*)(Bs + (wn*64 + nt*16 + l15)*72 + kc*32 + q*8);
            #pragma unroll
            for (int mt = 0; mt < 4; mt++)
                acc[mt*4+nt] = __builtin_amdgcn_mfma_f32_16x16x32_bf16(af[mt], bf_, acc[mt*4+nt], 0, 0, 0);
        }
    }
    __syncthreads();   // all As/Bs reads done -> overlay Cs
    #pragma unroll
    for (int mt = 0; mt < 4; mt++)
        #pragma unroll
        for (int nt = 0; nt < 4; nt++)
            #pragma unroll
            for (int e = 0; e < 4; e++){
                int row2 = mt*16 + q*4 + e;
                float v = acc[mt*4+nt][e] * msk[wm*64 + row2];
                Cs[w*4608 + row2*72 + nt*16 + l15] = f2bf(v);
            }
    __syncthreads();
    #pragma unroll
    for (int it = 0; it < 8; it++){
        int flat = lane + it*64;               // [0,512)
        int rr = flat >> 3, c8 = flat & 7;
        uint4 v = *(const uint4*)(Cs + w*4608 + rr*72 + c8*8);
        size_t dst = (size_t)(m0 + wm*64 + rr)*8192 + s*4096 + n0 + wn*64 + c8*8;
        *(uint4*)(Tg + dst) = v;
    }
}

// ---------------- radial MLP -> R[z][a][b][h] bf16 (16x16 pair tile per block)
// h2 B-fragments (rW2^T) live in registers; no per-block transpose.
__global__ __launch_bounds__(256,3) void k_radial(
    const float* __restrict__ geom,
    const float* __restrict__ rW1, const float* __restrict__ rb1,
    const unsigned short* __restrict__ w2T, const float* __restrict__ rb2,
    unsigned short* __restrict__ Rc)
{
    __shared__ unsigned short H[256*72];      // h1, then R tile (36.9 KB)
    __shared__ float W1s[NBAS*64];            // 10.2 KB
    __shared__ float rb1s[64], rb2s[64];
    __shared__ float pc0s[256], pc1s[256];
    __shared__ int po0s[256], po1s[256];
    __shared__ float gx[16],gy[16],gz[16],hx[16],hy[16],hz[16];

    int tid = threadIdx.x;
    int z = blockIdx.x;
    int ta = blockIdx.y % 12, tb = blockIdx.y / 12;
    int a0 = ta*16, b0 = tb*16;
    int lane = tid & 63, w = tid >> 6, q = lane >> 4, l15 = lane & 15;

    // B-fragments from global (coalesced: 16 rows x 64B per load)
    bf16x8 bfr[2][4];
    #pragma unroll
    for (int kc = 0; kc < 2; kc++)
        #pragma unroll
        for (int nt = 0; nt < 4; nt++)
            bfr[kc][nt] = *(const bf16x8*)(w2T + (nt*16 + l15)*64 + kc*32 + q*8);

    #pragma unroll
    for (int i = 0; i < 10; i++) W1s[tid + i*256] = rW1[tid + i*256];
    if (tid < 64){ rb1s[tid] = rb1[tid]; rb2s[tid] = rb2[tid]; }
    if (tid < 16){
        int g = (z*NATOMS + a0 + tid)*3;
        gx[tid] = geom[g]; gy[tid] = geom[g+1]; gz[tid] = geom[g+2];
    } else if (tid < 32){
        int t2 = tid - 16;
        int g = (z*NATOMS + b0 + t2)*3;
        hx[t2] = geom[g]; hy[t2] = geom[g+1]; hz[t2] = geom[g+2];
    }
    __syncthreads();

    {   // pair coefficients (2-sparse cosine basis)
        int a_l = tid >> 4, b_l = tid & 15;
        float dx = gx[a_l]-hx[b_l], dy = gy[a_l]-hy[b_l], dz = gz[a_l]-hz[b_l];
        float r = sqrtf(dx*dx + dy*dy + dz*dz);
        float u = r * 3.9f;
        int k0 = (int)u;
        float fr = u - (float)k0;
        float cs = __cosf(fr * 1.57079632679489662f);
        float c0 = cs*cs, c1 = 1.f - c0;
        if (k0   >= NBAS) c0 = 0.f;
        if (k0+1 >= NBAS) c1 = 0.f;
        pc0s[tid] = c0; pc1s[tid] = c1;
        po0s[tid] = min(k0, NBAS-1)*64;
        po1s[tid] = min(k0+1, NBAS-1)*64;
    }
    __syncthreads();

    float bias1 = rb1s[lane];
    #pragma unroll 8
    for (int i = 0; i < 64; i++){
        int p = w*64 + i;
        float c0 = pc0s[p], c1 = pc1s[p];
        int o0 = po0s[p], o1 = po1s[p];
        float pre = bias1 + c0*W1s[o0 + lane] + c1*W1s[o1 + lane];
        H[p*72 + lane] = f2bf(sspf(pre));
    }
    __syncthreads();

    f32x4 acc[16];
    #pragma unroll
    for (int i = 0; i < 16; i++) acc[i] = (f32x4){0.f,0.f,0.f,0.f};
    #pragma unroll
    for (int kc = 0; kc < 2; kc++){
        bf16x8 af[4];
        #pragma unroll
        for (int mt = 0; mt < 4; mt++)
            af[mt] = *(const bf16x8*)(H + ((w*4 + mt)*16 + l15)*72 + kc*32 + q*8);
        #pragma unroll
        for (int nt = 0; nt < 4; nt++){
            #pragma unroll
            for (int mt = 0; mt < 4; mt++)
                acc[mt*4+nt] = __builtin_amdgcn_mfma_f32_16x16x32_bf16(af[mt], bfr[kc][nt], acc[mt*4+nt], 0, 0, 0);
        }
    }
    __syncthreads();
    #pragma unroll
    for (int mt = 0; mt < 4; mt++)
        #pragma unroll
        for (int nt = 0; nt < 4; nt++){
            float b2 = rb2s[nt*16 + l15];
            #pragma unroll
            for (int e = 0; e < 4; e++){
                int p = (w*4 + mt)*16 + q*4 + e;
                H[p*72 + nt*16 + l15] = f2bf(sspf(acc[mt*4+nt][e] + b2));
            }
        }
    __syncthreads();
    // copy R tile out: R[z][a0+a_l][b0+b_l][h]
    #pragma unroll
    for (int it = 0; it < 8; it++){
        int e = tid + it*256;                  // [0,2048) uint4s
        int a_l = e >> 7, b_l = (e >> 3) & 15, h0 = (e & 7)*8;
        uint4 v = *(const uint4*)(H + (a_l*16 + b_l)*72 + h0);
        size_t dst = ((size_t)(z*NATOMS + a0 + a_l)*NATOMS + b0 + b_l)*64 + h0;
        *(uint4*)(Rc + dst) = v;
    }
}

// ---------------- contraction: part[z][kc][a][j2] (bf16) = sum_{k in chunk} R[a][k]*T[k][j2]
__global__ __launch_bounds__(256,3) void k_contract(
    const unsigned short* __restrict__ Rc, const unsigned short* __restrict__ Tc,
    unsigned short* __restrict__ part)
{
    __shared__ unsigned short sm[2*6912 + 2*4608];
    // A buf0 [0,6912) | A buf1 [6912,13824) | B buf0 [13824,18432) | B buf1 [18432,23040)

    int tid = threadIdx.x;
    int zl = blockIdx.x, kc = blockIdx.y;
    int lane = tid & 63, w = tid >> 6, q = lane >> 4, l15 = lane & 15;

    f32x4 acc[24];
    #pragma unroll
    for (int i = 0; i < 24; i++) acc[i] = (f32x4){0.f,0.f,0.f,0.f};

    const size_t Rbase = (size_t)zl*NATOMS*12288;
    const size_t Tbase = (size_t)zl*NATOMS*8192;

    #define STAGE(BUF, KS) { \
        int aoff_ = (BUF)*6912; int boff_ = 13824 + (BUF)*4608; \
        int b_ = kc*6 + ((KS) >> 1); int h0_ = ((KS) & 1)*32; \
        const unsigned short* Ab = Rc + Rbase + (size_t)b_*64 + h0_; \
        _Pragma("unroll") \
        for (int r_ = 0; r_ < 3; r_++){ \
            int idx = tid + r_*256; int a_ = idx >> 2, c8_ = idx & 3; \
            *(uint4*)(sm + aoff_ + a_*36 + c8_*8) = *(const uint4*)(Ab + (size_t)a_*12288 + c8_*8); \
        } \
        const unsigned short* Bb = Tc + Tbase + (size_t)b_*8192 + h0_; \
        _Pragma("unroll") \
        for (int r_ = 0; r_ < 2; r_++){ \
            int idx = tid + r_*256; int j_ = idx >> 2, c8_ = idx & 3; \
            *(uint4*)(sm + boff_ + j_*36 + c8_*8) = *(const uint4*)(Bb + (size_t)j_*64 + c8_*8); \
        } }

    STAGE(0, 0)
    __syncthreads();
    for (int ks = 0; ks < 12; ks++){
        int buf = ks & 1;
        if (ks < 11) STAGE(buf^1, ks+1)
        int aoff = buf*6912, boff = 13824 + buf*4608;
        bf16x8 af[3];
        #pragma unroll
        for (int mt = 0; mt < 3; mt++)
            af[mt] = *(const bf16x8*)(sm + aoff + (w*48 + mt*16 + l15)*36 + q*8);
        #pragma unroll
        for (int nt = 0; nt < 8; nt++){
            bf16x8 bf_ = *(const bf16x8*)(sm + boff + (nt*16 + l15)*36 + q*8);
            #pragma unroll
            for (int mt = 0; mt < 3; mt++)
                acc[mt*8+nt] = __builtin_amdgcn_mfma_f32_16x16x32_bf16(af[mt], bf_, acc[mt*8+nt], 0, 0, 0);
        }
        __syncthreads();
    }
    unsigned short* pbase = part + ((size_t)(zl*NKC + kc)*NATOMS)*128;
    #pragma unroll
    for (int mt = 0; mt < 3; mt++)
        #pragma unroll
        for (int nt = 0; nt < 8; nt++)
            #pragma unroll
            for (int e = 0; e < 4; e++){
                int a = w*48 + mt*16 + q*4 + e;
                int j2 = nt*16 + l15;
                pbase[a*128 + j2] = f2bf(acc[mt*8+nt][e]);
            }
    #undef STAGE
}

// ---------------- reduce partials + sp + mask -> bf16 next features
__global__ void k_reduceB(const unsigned short* __restrict__ part, const float* __restrict__ mask,
                          unsigned short* __restrict__ fb, unsigned short* __restrict__ fc){
    int zl = blockIdx.y;
    int idx = blockIdx.x*256 + threadIdx.x;    // [0, 24576)
    int a = idx >> 7, j2 = idx & 127;
    const unsigned short* p = part + ((size_t)(zl*NKC)*NATOMS + a)*128 + j2;
    float s = 0.f;
    #pragma unroll
    for (int c = 0; c < NKC; c++) s += bf2f(p[(size_t)c*NATOMS*128]);
    int rowg = zl*NATOMS + a;
    float v = spf_act(s) * mask[rowg];
    if (j2 < 64) fb[rowg*64 + j2] = f2bf(v);
    else         fc[rowg*64 + j2 - 64] = f2bf(v);
}

// ---------------- fused head: h1 + BN1 + leaky + h2 + BN2 + leaky + mask -> y2
// one block per atom; BN axes are (z, feat) per atom == block-local
__global__ __launch_bounds__(256) void k_head(
    const unsigned short* __restrict__ fbio, const unsigned short* __restrict__ fch,
    const float* __restrict__ fW1, const float* __restrict__ fb1,
    const float* __restrict__ fW2, const float* __restrict__ fb2,
    const float* __restrict__ mask, float* __restrict__ y2)
{
    __shared__ float X[2048];
    __shared__ float red[16];
    __shared__ float stats[2];
    int a = blockIdx.x, tid = threadIdx.x;
    int lane = tid & 63, w = tid >> 6;

    #pragma unroll
    for (int i = 0; i < 8; i++){
        int idx = tid + i*256; int z = idx >> 7, c = idx & 127;
        int row = z*NATOMS + a;
        X[idx] = (c < 64) ? bf2f(fbio[row*64 + c]) : bf2f(fch[row*64 + c - 64]);
    }
    __syncthreads();
    // h1: 2 float4 outputs per thread
    f32x4 v[2]; float s = 0.f, ss = 0.f;
    #pragma unroll
    for (int i = 0; i < 2; i++){
        int idx4 = tid + i*256; int z = idx4 >> 5, k4 = (idx4 & 31)*4;
        f32x4 acc = { fb1[k4], fb1[k4+1], fb1[k4+2], fb1[k4+3] };
        #pragma unroll 4
        for (int c = 0; c < 128; c++){
            float xv = X[z*128 + c];
            float4 wv = *(const float4*)(fW1 + (size_t)c*128 + k4);
            acc[0] += xv*wv.x; acc[1] += xv*wv.y; acc[2] += xv*wv.z; acc[3] += xv*wv.w;
        }
        v[i] = acc;
        s += acc[0]+acc[1]+acc[2]+acc[3];
        ss += acc[0]*acc[0]+acc[1]*acc[1]+acc[2]*acc[2]+acc[3]*acc[3];
    }
    for (int off = 32; off; off >>= 1){ s += __shfl_down(s, off); ss += __shfl_down(ss, off); }
    if (!lane){ red[w] = s; red[8+w] = ss; }
    __syncthreads();
    if (!tid){
        float S = red[0]+red[1]+red[2]+red[3];
        float SS = red[8]+red[9]+red[10]+red[11];
        float m = S*(1.f/2048.f), var = SS*(1.f/2048.f) - m*m;
        stats[0] = m; stats[1] = rsqrtf(var + 1e-5f);
    }
    __syncthreads();
    float m1 = stats[0], inv1 = stats[1];
    #pragma unroll
    for (int i = 0; i < 2; i++){
        int idx4 = tid + i*256;
        f32x4 t;
        #pragma unroll
        for (int e = 0; e < 4; e++){
            float x = (v[i][e]-m1)*inv1;
            t[e] = (x > 0.f) ? x : 0.2f*x;
        }
        *(f32x4*)(X + idx4*4) = t;
    }
    __syncthreads();
    // h2: 2 outputs per thread
    float u[2]; s = 0.f; ss = 0.f;
    #pragma unroll
    for (int i = 0; i < 2; i++){
        int idx = tid + i*256; int z = idx >> 5, j = idx & 31;
        float acc = fb2[j];
        #pragma unroll 8
        for (int k = 0; k < 128; k++) acc += X[z*128 + k]*fW2[k*32 + j];
        u[i] = acc; s += acc; ss += acc*acc;
    }
    for (int off = 32; off; off >>= 1){ s += __shfl_down(s, off); ss += __shfl_down(ss, off); }
    if (!lane){ red[w] = s; red[8+w] = ss; }
    __syncthreads();
    if (!tid){
        float S = red[0]+red[1]+red[2]+red[3];
        float SS = red[8]+red[9]+red[10]+red[11];
        float m = S*(1.f/512.f), var = SS*(1.f/512.f) - m*m;
        stats[0] = m; stats[1] = rsqrtf(var + 1e-5f);
    }
    __syncthreads();
    float m2 = stats[0], inv2 = stats[1];
    #pragma unroll
    for (int i = 0; i < 2; i++){
        int idx = tid + i*256; int z = idx >> 5, j = idx & 31;
        float x = (u[i]-m2)*inv2;
        x = (x > 0.f) ? x : 0.2f*x;
        y2[(size_t)(z*NATOMS + a)*32 + j] = x * mask[z*NATOMS + a];
    }
}

// ---------------- out[z,j] = sum_a y2[z,a,j]
__global__ void k_sum(const float* __restrict__ y2, float* __restrict__ out){
    int e = blockIdx.x;           // 512 outputs
    int z = e >> 5, jj = e & 31;
    int tid = threadIdx.x;        // 64
    float s = 0.f;
    for (int a = tid; a < NATOMS; a += 64) s += y2[(z*NATOMS + a)*32 + jj];
    for (int off = 32; off; off >>= 1) s += __shfl_down(s, off);
    if (!tid) out[e] = s;
}

extern "C" void kernel_launch(void* const* d_in, const int* in_sizes, int n_in,
                              void* d_out, int out_size, void* d_ws, size_t ws_size,
                              hipStream_t stream){
    const float* features = (const float*)d_in[0];
    const float* geometry = (const float*)d_in[1];
    const float* mask     = (const float*)d_in[2];
    const float* W_bio    = (const float*)d_in[3];
    const float* b_bio    = (const float*)d_in[4];
    const float* W_ch     = (const float*)d_in[5];
    const float* b_ch     = (const float*)d_in[6];
    const float* rW1[2] = {(const float*)d_in[7],  (const float*)d_in[12]};
    const float* rb1[2] = {(const float*)d_in[8],  (const float*)d_in[13]};
    const float* rW2[2] = {(const float*)d_in[9],  (const float*)d_in[14]};
    const float* rb2[2] = {(const float*)d_in[10], (const float*)d_in[15]};
    const float* rWo[2] = {(const float*)d_in[11], (const float*)d_in[16]};
    const float* fW1 = (const float*)d_in[17];
    const float* fb1 = (const float*)d_in[18];
    const float* fW2 = (const float*)d_in[19];
    const float* fb2 = (const float*)d_in[20];

    char* ws = (char*)d_ws;
    unsigned short* fAb = (unsigned short*)ws;   ws += (size_t)ZA*64*2;
    unsigned short* fAc = (unsigned short*)ws;   ws += (size_t)ZA*64*2;
    unsigned short* fBb = (unsigned short*)ws;   ws += (size_t)ZA*64*2;
    unsigned short* fBc = (unsigned short*)ws;   ws += (size_t)ZA*64*2;
    unsigned short* w2T = (unsigned short*)ws;   ws += (size_t)4096*2;
    unsigned short* Tg = (unsigned short*)ws;    ws += (size_t)ZA*8192*2;            // 50.3 MB
    unsigned short* Rc = (unsigned short*)ws;    ws += (size_t)ZB*NATOMS*NATOMS*64*2; // 75.5 MB
    unsigned short* part = (unsigned short*)ws;  ws += (size_t)ZB*NKC*NATOMS*128*2;   // 25.2 MB
    float* y2 = (float*)ws;                      ws += (size_t)ZA*32*4;

    dim3 gt(24, 32, 2);
    dim3 gr(ZB, 144);
    dim3 gc(ZB, NKC);
    dim3 gd(96, ZB);
    // layer 0 (encode fused into tmpB)
    k_prep2<<<16, 256, 0, stream>>>(rW2[0], w2T);
    k_tmpB<<<gt, 256, 0, stream>>>(nullptr, nullptr, features, W_bio, b_bio, W_ch, b_ch,
                                   mask, rWo[0], Tg);
    k_radial<<<gr, 256, 0, stream>>>(geometry, rW1[0], rb1[0], w2T, rb2[0], Rc);
    k_contract<<<gc, 256, 0, stream>>>(Rc, Tg, part);
    k_reduceB<<<gd, 256, 0, stream>>>(part, mask, fAb, fAc);
    // layer 1
    k_prep2<<<16, 256, 0, stream>>>(rW2[1], w2T);
    k_tmpB<<<gt, 256, 0, stream>>>(fAb, fAc, nullptr, W_bio, b_bio, W_ch, b_ch,
                                   mask, rWo[1], Tg);
    k_radial<<<gr, 256, 0, stream>>>(geometry, rW1[1], rb1[1], w2T, rb2[1], Rc);
    k_contract<<<gc, 256, 0, stream>>>(Rc, Tg, part);
    k_reduceB<<<gd, 256, 0, stream>>>(part, mask, fBb, fBc);
    // fused head + final sum
    k_head<<<NATOMS, 256, 0, stream>>>(fBb, fBc, fW1, fb1, fW2, fb2, mask, y2);
    k_sum<<<512, 64, 0, stream>>>(y2, (float*)d_out);
}

// Round 8
// 374.200 us; speedup vs baseline: 1.0173x; 1.0173x over previous
//
#include <hip/hip_runtime.h>
#include <math.h>

#define ZB 16
#define NATOMS 192
#define NBAS 40
#define ZA (ZB*NATOMS)       // 3072
#define NKC 32               // K-chunks in contraction

typedef __attribute__((ext_vector_type(4))) float f32x4;
typedef __attribute__((ext_vector_type(8))) short bf16x8;

__device__ __forceinline__ unsigned short f2bf(float x){
    union { float f; unsigned u; } v; v.f = x;
    unsigned r = v.u + 0x7FFFu + ((v.u >> 16) & 1u);
    return (unsigned short)(r >> 16);
}
__device__ __forceinline__ float bf2f(unsigned short u){
    union { unsigned u; float f; } v; v.u = ((unsigned)u) << 16; return v.f;
}
// ssp(x) = softplus(5x)/5 - ln2/5 via hw exp2/log2
__device__ __forceinline__ float sspf(float x){
    float t = 7.2134752f*x;
    float tc = fminf(t, 126.f);
    float e = __builtin_amdgcn_exp2f(tc);
    float l = __builtin_amdgcn_logf(1.f + e);   // log2
    float r = fmaf(l, 0.13862944f, -0.13862944f);
    return (t > 126.f) ? (x - 0.13862944f) : r;
}
__device__ __forceinline__ float spf_act(float x){
    float t = 7.2134752f*x;
    float tc = fminf(t, 126.f);
    float e = __builtin_amdgcn_exp2f(tc);
    float l = __builtin_amdgcn_logf(1.f + e);
    float r = l*0.13862944f;
    return (t > 126.f) ? x : r;
}

// ---------------- prep: w2T[hout*64+hin] = bf16(rW2[hin][hout])
__global__ void k_prep2(const float* __restrict__ rW2, unsigned short* __restrict__ w2T){
    int idx = blockIdx.x*256 + threadIdx.x;     // [0,4096)
    int hout = idx >> 6, hin = idx & 63;
    w2T[idx] = f2bf(rW2[hin*64 + hout]);
}

// ---------------- tmp GEMM bf16 MFMA: Tg[m][s*4096 + j*64 + h] = (f_s[m] @ rWo[h][j][:]) * mask*c
// layer 0 (feat != null): f_s rows computed on the fly from the linear encoders.
__global__ __launch_bounds__(256,2) void k_tmpB(
    const unsigned short* __restrict__ fb, const unsigned short* __restrict__ fc,
    const float* __restrict__ feat,
    const float* __restrict__ Wb, const float* __restrict__ bb,
    const float* __restrict__ Wc, const float* __restrict__ bc,
    const float* __restrict__ mask, const float* __restrict__ rWo,
    unsigned short* __restrict__ Tg)
{
    __shared__ unsigned short sm[18432];   // As[128*72] | Bs[128*72]; Cs overlays all
    __shared__ float msk[128];
    __shared__ float featS[128*8];
    __shared__ float WbS[7*64];
    __shared__ float bbS[64], WcS[64], bcS[64];
    unsigned short* As = sm;
    unsigned short* Bs = sm + 9216;
    unsigned short* Cs = sm;

    int tid = threadIdx.x;
    int m0 = blockIdx.x*128, n0 = blockIdx.y*128, s = blockIdx.z;
    int lane = tid & 63, w = tid >> 6, q = lane >> 4, l15 = lane & 15;
    int wm = w & 1, wn = w >> 1;

    if (feat){
        // stage encoder inputs
        #pragma unroll
        for (int it = 0; it < 4; it++){
            int idx = tid + it*256;            // 1024 floats
            featS[idx] = feat[(size_t)m0*8 + idx];
        }
        for (int i = tid; i < 448; i += 256) WbS[i] = Wb[i];   // 7x64, strided
        if (tid < 64){ bbS[tid] = bb[tid]; WcS[tid] = Wc[tid]; bcS[tid] = bc[tid]; }
        __syncthreads();
        #pragma unroll
        for (int it = 0; it < 32; it++){
            int idx = tid + it*256;            // 8192
            int r = idx >> 6, e = idx & 63;
            float acc;
            if (s == 0){
                acc = bbS[e];
                #pragma unroll
                for (int c = 0; c < 7; c++) acc += featS[r*8+c]*WbS[c*64+e];
            } else {
                acc = bcS[e] + featS[r*8+7]*WcS[e];
            }
            As[r*72 + e] = f2bf(acc);
        }
    } else {
        const unsigned short* f = s ? fc : fb;
        #pragma unroll
        for (int it = 0; it < 4; it++){
            int idx = tid + it*256;            // 1024 uint4
            int r = idx >> 3, c8 = idx & 7;
            *(uint4*)(As + r*72 + c8*8) = *(const uint4*)(f + (size_t)(m0 + r)*64 + c8*8);
        }
    }
    // B-staging: row r -> n = n0+r = j*64+h -> rWo[(h*64+j)*64 + i], fp32->bf16
    #pragma unroll
    for (int it = 0; it < 8; it++){
        int idx = tid + it*256;                // 2048 float4
        int r = idx >> 4, c4 = idx & 15;
        int n = n0 + r;
        int j = n >> 6, h = n & 63;
        float4 v = *(const float4*)(rWo + (size_t)(h*64 + j)*64 + c4*4);
        ushort4 o; o.x = f2bf(v.x); o.y = f2bf(v.y); o.z = f2bf(v.z); o.w = f2bf(v.w);
        *(ushort4*)(Bs + r*72 + c4*4) = o;
    }
    if (tid < 128) msk[tid] = mask[m0 + tid] * 0.07216878364870322f;
    __syncthreads();

    f32x4 acc[16];
    #pragma unroll
    for (int i = 0; i < 16; i++) acc[i] = (f32x4){0.f,0.f,0.f,0.f};
    #pragma unroll
    for (int kc = 0; kc < 2; kc++){
        bf16x8 af[4];
        #pragma unroll
        for (int mt = 0; mt < 4; mt++)
            af[mt] = *(const bf16x8*)(As + (wm*64 + mt*16 + l15)*72 + kc*32 + q*8);
        #pragma unroll
        for (int nt = 0; nt < 4; nt++){
            bf16x8 bf_ = *(const bf16x8*)(Bs + (wn*64 + nt*16 + l15)*72 + kc*32 + q*8);
            #pragma unroll
            for (int mt = 0; mt < 4; mt++)
                acc[mt*4+nt] = __builtin_amdgcn_mfma_f32_16x16x32_bf16(af[mt], bf_, acc[mt*4+nt], 0, 0, 0);
        }
    }
    __syncthreads();   // all As/Bs reads done -> overlay Cs
    #pragma unroll
    for (int mt = 0; mt < 4; mt++)
        #pragma unroll
        for (int nt = 0; nt < 4; nt++)
            #pragma unroll
            for (int e = 0; e < 4; e++){
                int row2 = mt*16 + q*4 + e;
                float v = acc[mt*4+nt][e] * msk[wm*64 + row2];
                Cs[w*4608 + row2*72 + nt*16 + l15] = f2bf(v);
            }
    __syncthreads();
    #pragma unroll
    for (int it = 0; it < 8; it++){
        int flat = lane + it*64;               // [0,512)
        int rr = flat >> 3, c8 = flat & 7;
        uint4 v = *(const uint4*)(Cs + w*4608 + rr*72 + c8*8);
        size_t dst = (size_t)(m0 + wm*64 + rr)*8192 + s*4096 + n0 + wn*64 + c8*8;
        *(uint4*)(Tg + dst) = v;
    }
}

// ---------------- radial MLP -> R[z][b][a][h] bf16 (b-major for contract coalescing)
// h2 B-fragments (rW2^T) live in registers; no per-block transpose.
__global__ __launch_bounds__(256,3) void k_radial(
    const float* __restrict__ geom,
    const float* __restrict__ rW1, const float* __restrict__ rb1,
    const unsigned short* __restrict__ w2T, const float* __restrict__ rb2,
    unsigned short* __restrict__ Rc)
{
    __shared__ unsigned short H[256*72];      // h1, then R tile (36.9 KB)
    __shared__ float W1s[NBAS*64];            // 10.2 KB
    __shared__ float rb1s[64], rb2s[64];
    __shared__ float pc0s[256], pc1s[256];
    __shared__ int po0s[256], po1s[256];
    __shared__ float gx[16],gy[16],gz[16],hx[16],hy[16],hz[16];

    int tid = threadIdx.x;
    int z = blockIdx.x;
    int ta = blockIdx.y % 12, tb = blockIdx.y / 12;
    int a0 = ta*16, b0 = tb*16;
    int lane = tid & 63, w = tid >> 6, q = lane >> 4, l15 = lane & 15;

    // B-fragments from global (coalesced: 16 rows x 64B per load)
    bf16x8 bfr[2][4];
    #pragma unroll
    for (int kc = 0; kc < 2; kc++)
        #pragma unroll
        for (int nt = 0; nt < 4; nt++)
            bfr[kc][nt] = *(const bf16x8*)(w2T + (nt*16 + l15)*64 + kc*32 + q*8);

    #pragma unroll
    for (int i = 0; i < 10; i++) W1s[tid + i*256] = rW1[tid + i*256];
    if (tid < 64){ rb1s[tid] = rb1[tid]; rb2s[tid] = rb2[tid]; }
    if (tid < 16){
        int g = (z*NATOMS + a0 + tid)*3;
        gx[tid] = geom[g]; gy[tid] = geom[g+1]; gz[tid] = geom[g+2];
    } else if (tid < 32){
        int t2 = tid - 16;
        int g = (z*NATOMS + b0 + t2)*3;
        hx[t2] = geom[g]; hy[t2] = geom[g+1]; hz[t2] = geom[g+2];
    }
    __syncthreads();

    {   // pair coefficients (2-sparse cosine basis)
        int a_l = tid >> 4, b_l = tid & 15;
        float dx = gx[a_l]-hx[b_l], dy = gy[a_l]-hy[b_l], dz = gz[a_l]-hz[b_l];
        float r = sqrtf(dx*dx + dy*dy + dz*dz);
        float u = r * 3.9f;
        int k0 = (int)u;
        float fr = u - (float)k0;
        float cs = __cosf(fr * 1.57079632679489662f);
        float c0 = cs*cs, c1 = 1.f - c0;
        if (k0   >= NBAS) c0 = 0.f;
        if (k0+1 >= NBAS) c1 = 0.f;
        pc0s[tid] = c0; pc1s[tid] = c1;
        po0s[tid] = min(k0, NBAS-1)*64;
        po1s[tid] = min(k0+1, NBAS-1)*64;
    }
    __syncthreads();

    float bias1 = rb1s[lane];
    #pragma unroll 8
    for (int i = 0; i < 64; i++){
        int p = w*64 + i;
        float c0 = pc0s[p], c1 = pc1s[p];
        int o0 = po0s[p], o1 = po1s[p];
        float pre = bias1 + c0*W1s[o0 + lane] + c1*W1s[o1 + lane];
        H[p*72 + lane] = f2bf(sspf(pre));
    }
    __syncthreads();

    f32x4 acc[16];
    #pragma unroll
    for (int i = 0; i < 16; i++) acc[i] = (f32x4){0.f,0.f,0.f,0.f};
    #pragma unroll
    for (int kc = 0; kc < 2; kc++){
        bf16x8 af[4];
        #pragma unroll
        for (int mt = 0; mt < 4; mt++)
            af[mt] = *(const bf16x8*)(H + ((w*4 + mt)*16 + l15)*72 + kc*32 + q*8);
        #pragma unroll
        for (int nt = 0; nt < 4; nt++){
            #pragma unroll
            for (int mt = 0; mt < 4; mt++)
                acc[mt*4+nt] = __builtin_amdgcn_mfma_f32_16x16x32_bf16(af[mt], bfr[kc][nt], acc[mt*4+nt], 0, 0, 0);
        }
    }
    __syncthreads();
    #pragma unroll
    for (int mt = 0; mt < 4; mt++)
        #pragma unroll
        for (int nt = 0; nt < 4; nt++){
            float b2 = rb2s[nt*16 + l15];
            #pragma unroll
            for (int e = 0; e < 4; e++){
                int p = (w*4 + mt)*16 + q*4 + e;
                H[p*72 + nt*16 + l15] = f2bf(sspf(acc[mt*4+nt][e] + b2));
            }
        }
    __syncthreads();
    // copy R tile out b-major: R[z][b0+b_l][a0+a_l][h]
    #pragma unroll
    for (int it = 0; it < 8; it++){
        int e = tid + it*256;                  // [0,2048) uint4s
        int a_l = e >> 7, b_l = (e >> 3) & 15, h0 = (e & 7)*8;
        uint4 v = *(const uint4*)(H + (a_l*16 + b_l)*72 + h0);
        size_t dst = ((size_t)(z*NATOMS + b0 + b_l)*NATOMS + a0 + a_l)*64 + h0;
        *(uint4*)(Rc + dst) = v;
    }
}

// ---------------- contraction: part[z][kc][a][j2] (bf16) = sum_{b in chunk} R[z][b]·T[z][b]
// R b-major: per-b A tile (192x64) fully contiguous; single LDS buffer + register prefetch.
__global__ __launch_bounds__(256,2) void k_contract(
    const unsigned short* __restrict__ Rc, const unsigned short* __restrict__ Tc,
    unsigned short* __restrict__ part)
{
    __shared__ unsigned short smA[192*72];   // 27648 B
    __shared__ unsigned short smB[128*72];   // 18432 B

    int tid = threadIdx.x;
    int zl = blockIdx.x, kc = blockIdx.y;
    int lane = tid & 63, w = tid >> 6, q = lane >> 4, l15 = lane & 15;
    int a_r = tid >> 3, c8 = tid & 7;        // staging coords

    f32x4 acc[24];
    #pragma unroll
    for (int i = 0; i < 24; i++) acc[i] = (f32x4){0.f,0.f,0.f,0.f};

    const size_t Rbase = (size_t)zl*NATOMS*NATOMS*64;
    const size_t Tbase = (size_t)zl*NATOMS*8192;

    uint4 ra[6], rb[4];
    {   // prefetch first b
        const unsigned short* Ab = Rc + Rbase + (size_t)(kc*6)*NATOMS*64;
        #pragma unroll
        for (int r = 0; r < 6; r++) ra[r] = *(const uint4*)(Ab + (size_t)(a_r + 32*r)*64 + c8*8);
        const unsigned short* Bb = Tc + Tbase + (size_t)(kc*6)*8192;
        #pragma unroll
        for (int r = 0; r < 4; r++) rb[r] = *(const uint4*)(Bb + (size_t)(a_r + 32*r)*64 + c8*8);
    }
    for (int i = 0; i < 6; i++){
        __syncthreads();   // previous MFMA LDS reads complete
        #pragma unroll
        for (int r = 0; r < 6; r++) *(uint4*)(smA + (a_r + 32*r)*72 + c8*8) = ra[r];
        #pragma unroll
        for (int r = 0; r < 4; r++) *(uint4*)(smB + (a_r + 32*r)*72 + c8*8) = rb[r];
        if (i < 5){
            int b = kc*6 + i + 1;
            const unsigned short* Ab = Rc + Rbase + (size_t)b*NATOMS*64;
            #pragma unroll
            for (int r = 0; r < 6; r++) ra[r] = *(const uint4*)(Ab + (size_t)(a_r + 32*r)*64 + c8*8);
            const unsigned short* Bb = Tc + Tbase + (size_t)b*8192;
            #pragma unroll
            for (int r = 0; r < 4; r++) rb[r] = *(const uint4*)(Bb + (size_t)(a_r + 32*r)*64 + c8*8);
        }
        __syncthreads();   // LDS tile ready
        #pragma unroll
        for (int kq = 0; kq < 2; kq++){
            bf16x8 af[3];
            #pragma unroll
            for (int mt = 0; mt < 3; mt++)
                af[mt] = *(const bf16x8*)(smA + (w*48 + mt*16 + l15)*72 + kq*32 + q*8);
            #pragma unroll
            for (int nt = 0; nt < 8; nt++){
                bf16x8 bf_ = *(const bf16x8*)(smB + (nt*16 + l15)*72 + kq*32 + q*8);
                #pragma unroll
                for (int mt = 0; mt < 3; mt++)
                    acc[mt*8+nt] = __builtin_amdgcn_mfma_f32_16x16x32_bf16(af[mt], bf_, acc[mt*8+nt], 0, 0, 0);
            }
        }
    }
    unsigned short* pbase = part + ((size_t)(zl*NKC + kc)*NATOMS)*128;
    #pragma unroll
    for (int mt = 0; mt < 3; mt++)
        #pragma unroll
        for (int nt = 0; nt < 8; nt++)
            #pragma unroll
            for (int e = 0; e < 4; e++){
                int a = w*48 + mt*16 + q*4 + e;
                int j2 = nt*16 + l15;
                pbase[a*128 + j2] = f2bf(acc[mt*8+nt][e]);
            }
}

// ---------------- reduce partials + sp + mask -> bf16 next features
__global__ void k_reduceB(const unsigned short* __restrict__ part, const float* __restrict__ mask,
                          unsigned short* __restrict__ fb, unsigned short* __restrict__ fc){
    int zl = blockIdx.y;
    int idx = blockIdx.x*256 + threadIdx.x;    // [0, 24576)
    int a = idx >> 7, j2 = idx & 127;
    const unsigned short* p = part + ((size_t)(zl*NKC)*NATOMS + a)*128 + j2;
    float s = 0.f;
    #pragma unroll
    for (int c = 0; c < NKC; c++) s += bf2f(p[(size_t)c*NATOMS*128]);
    int rowg = zl*NATOMS + a;
    float v = spf_act(s) * mask[rowg];
    if (j2 < 64) fb[rowg*64 + j2] = f2bf(v);
    else         fc[rowg*64 + j2 - 64] = f2bf(v);
}

// ---------------- fused head: h1 + BN1 + leaky + h2 + BN2 + leaky + mask -> y2
__global__ __launch_bounds__(256) void k_head(
    const unsigned short* __restrict__ fbio, const unsigned short* __restrict__ fch,
    const float* __restrict__ fW1, const float* __restrict__ fb1,
    const float* __restrict__ fW2, const float* __restrict__ fb2,
    const float* __restrict__ mask, float* __restrict__ y2)
{
    __shared__ float X[2048];
    __shared__ float red[16];
    __shared__ float stats[2];
    int a = blockIdx.x, tid = threadIdx.x;
    int lane = tid & 63, w = tid >> 6;

    #pragma unroll
    for (int i = 0; i < 8; i++){
        int idx = tid + i*256; int z = idx >> 7, c = idx & 127;
        int row = z*NATOMS + a;
        X[idx] = (c < 64) ? bf2f(fbio[row*64 + c]) : bf2f(fch[row*64 + c - 64]);
    }
    __syncthreads();
    // h1: 2 float4 outputs per thread
    f32x4 v[2]; float s = 0.f, ss = 0.f;
    #pragma unroll
    for (int i = 0; i < 2; i++){
        int idx4 = tid + i*256; int z = idx4 >> 5, k4 = (idx4 & 31)*4;
        f32x4 acc = { fb1[k4], fb1[k4+1], fb1[k4+2], fb1[k4+3] };
        #pragma unroll 4
        for (int c = 0; c < 128; c++){
            float xv = X[z*128 + c];
            float4 wv = *(const float4*)(fW1 + (size_t)c*128 + k4);
            acc[0] += xv*wv.x; acc[1] += xv*wv.y; acc[2] += xv*wv.z; acc[3] += xv*wv.w;
        }
        v[i] = acc;
        s += acc[0]+acc[1]+acc[2]+acc[3];
        ss += acc[0]*acc[0]+acc[1]*acc[1]+acc[2]*acc[2]+acc[3]*acc[3];
    }
    for (int off = 32; off; off >>= 1){ s += __shfl_down(s, off); ss += __shfl_down(ss, off); }
    if (!lane){ red[w] = s; red[8+w] = ss; }
    __syncthreads();
    if (!tid){
        float S = red[0]+red[1]+red[2]+red[3];
        float SS = red[8]+red[9]+red[10]+red[11];
        float m = S*(1.f/2048.f), var = SS*(1.f/2048.f) - m*m;
        stats[0] = m; stats[1] = rsqrtf(var + 1e-5f);
    }
    __syncthreads();
    float m1 = stats[0], inv1 = stats[1];
    #pragma unroll
    for (int i = 0; i < 2; i++){
        int idx4 = tid + i*256;
        f32x4 t;
        #pragma unroll
        for (int e = 0; e < 4; e++){
            float x = (v[i][e]-m1)*inv1;
            t[e] = (x > 0.f) ? x : 0.2f*x;
        }
        *(f32x4*)(X + idx4*4) = t;
    }
    __syncthreads();
    // h2: 2 outputs per thread
    float u[2]; s = 0.f; ss = 0.f;
    #pragma unroll
    for (int i = 0; i < 2; i++){
        int idx = tid + i*256; int z = idx >> 5, j = idx & 31;
        float acc = fb2[j];
        #pragma unroll 8
        for (int k = 0; k < 128; k++) acc += X[z*128 + k]*fW2[k*32 + j];
        u[i] = acc; s += acc; ss += acc*acc;
    }
    for (int off = 32; off; off >>= 1){ s += __shfl_down(s, off); ss += __shfl_down(ss, off); }
    if (!lane){ red[w] = s; red[8+w] = ss; }
    __syncthreads();
    if (!tid){
        float S = red[0]+red[1]+red[2]+red[3];
        float SS = red[8]+red[9]+red[10]+red[11];
        float m = S*(1.f/512.f), var = SS*(1.f/512.f) - m*m;
        stats[0] = m; stats[1] = rsqrtf(var + 1e-5f);
    }
    __syncthreads();
    float m2 = stats[0], inv2 = stats[1];
    #pragma unroll
    for (int i = 0; i < 2; i++){
        int idx = tid + i*256; int z = idx >> 5, j = idx & 31;
        float x = (u[i]-m2)*inv2;
        x = (x > 0.f) ? x : 0.2f*x;
        y2[(size_t)(z*NATOMS + a)*32 + j] = x * mask[z*NATOMS + a];
    }
}

// ---------------- out[z,j] = sum_a y2[z,a,j]
__global__ void k_sum(const float* __restrict__ y2, float* __restrict__ out){
    int e = blockIdx.x;           // 512 outputs
    int z = e >> 5, jj = e & 31;
    int tid = threadIdx.x;        // 64
    float s = 0.f;
    for (int a = tid; a < NATOMS; a += 64) s += y2[(z*NATOMS + a)*32 + jj];
    for (int off = 32; off; off >>= 1) s += __shfl_down(s, off);
    if (!tid) out[e] = s;
}

extern "C" void kernel_launch(void* const* d_in, const int* in_sizes, int n_in,
                              void* d_out, int out_size, void* d_ws, size_t ws_size,
                              hipStream_t stream){
    const float* features = (const float*)d_in[0];
    const float* geometry = (const float*)d_in[1];
    const float* mask     = (const float*)d_in[2];
    const float* W_bio    = (const float*)d_in[3];
    const float* b_bio    = (const float*)d_in[4];
    const float* W_ch     = (const float*)d_in[5];
    const float* b_ch     = (const float*)d_in[6];
    const float* rW1[2] = {(const float*)d_in[7],  (const float*)d_in[12]};
    const float* rb1[2] = {(const float*)d_in[8],  (const float*)d_in[13]};
    const float* rW2[2] = {(const float*)d_in[9],  (const float*)d_in[14]};
    const float* rb2[2] = {(const float*)d_in[10], (const float*)d_in[15]};
    const float* rWo[2] = {(const float*)d_in[11], (const float*)d_in[16]};
    const float* fW1 = (const float*)d_in[17];
    const float* fb1 = (const float*)d_in[18];
    const float* fW2 = (const float*)d_in[19];
    const float* fb2 = (const float*)d_in[20];

    char* ws = (char*)d_ws;
    unsigned short* fAb = (unsigned short*)ws;   ws += (size_t)ZA*64*2;
    unsigned short* fAc = (unsigned short*)ws;   ws += (size_t)ZA*64*2;
    unsigned short* fBb = (unsigned short*)ws;   ws += (size_t)ZA*64*2;
    unsigned short* fBc = (unsigned short*)ws;   ws += (size_t)ZA*64*2;
    unsigned short* w2T = (unsigned short*)ws;   ws += (size_t)4096*2;
    unsigned short* Tg = (unsigned short*)ws;    ws += (size_t)ZA*8192*2;            // 50.3 MB
    unsigned short* Rc = (unsigned short*)ws;    ws += (size_t)ZB*NATOMS*NATOMS*64*2; // 75.5 MB
    unsigned short* part = (unsigned short*)ws;  ws += (size_t)ZB*NKC*NATOMS*128*2;   // 25.2 MB
    float* y2 = (float*)ws;                      ws += (size_t)ZA*32*4;

    dim3 gt(24, 32, 2);
    dim3 gr(ZB, 144);
    dim3 gc(ZB, NKC);
    dim3 gd(96, ZB);
    // layer 0 (encode fused into tmpB)
    k_prep2<<<16, 256, 0, stream>>>(rW2[0], w2T);
    k_tmpB<<<gt, 256, 0, stream>>>(nullptr, nullptr, features, W_bio, b_bio, W_ch, b_ch,
                                   mask, rWo[0], Tg);
    k_radial<<<gr, 256, 0, stream>>>(geometry, rW1[0], rb1[0], w2T, rb2[0], Rc);
    k_contract<<<gc, 256, 0, stream>>>(Rc, Tg, part);
    k_reduceB<<<gd, 256, 0, stream>>>(part, mask, fAb, fAc);
    // layer 1
    k_prep2<<<16, 256, 0, stream>>>(rW2[1], w2T);
    k_tmpB<<<gt, 256, 0, stream>>>(fAb, fAc, nullptr, W_bio, b_bio, W_ch, b_ch,
                                   mask, rWo[1], Tg);
    k_radial<<<gr, 256, 0, stream>>>(geometry, rW1[1], rb1[1], w2T, rb2[1], Rc);
    k_contract<<<gc, 256, 0, stream>>>(Rc, Tg, part);
    k_reduceB<<<gd, 256, 0, stream>>>(part, mask, fBb, fBc);
    // fused head + final sum
    k_head<<<NATOMS, 256, 0, stream>>>(fBb, fBc, fW1, fb1, fW2, fb2, mask, y2);
    k_sum<<<512, 64, 0, stream>>>(y2, (float*)d_out);
}

// Round 9
// 359.618 us; speedup vs baseline: 1.0586x; 1.0405x over previous
//
#include <hip/hip_runtime.h>
#include <math.h>

#define ZB 16
#define NATOMS 192
#define NBAS 40
#define ZA (ZB*NATOMS)       // 3072
#define NKC 32               // K-chunks in contraction

typedef __attribute__((ext_vector_type(4))) float f32x4;
typedef __attribute__((ext_vector_type(8))) short bf16x8;

__device__ __forceinline__ unsigned short f2bf(float x){
    union { float f; unsigned u; } v; v.f = x;
    unsigned r = v.u + 0x7FFFu + ((v.u >> 16) & 1u);
    return (unsigned short)(r >> 16);
}
__device__ __forceinline__ float bf2f(unsigned short u){
    union { unsigned u; float f; } v; v.u = ((unsigned)u) << 16; return v.f;
}
// ssp(x) = softplus(5x)/5 - ln2/5 via hw exp2/log2
__device__ __forceinline__ float sspf(float x){
    float t = 7.2134752f*x;
    float tc = fminf(t, 126.f);
    float e = __builtin_amdgcn_exp2f(tc);
    float l = __builtin_amdgcn_logf(1.f + e);   // log2
    float r = fmaf(l, 0.13862944f, -0.13862944f);
    return (t > 126.f) ? (x - 0.13862944f) : r;
}
__device__ __forceinline__ float spf_act(float x){
    float t = 7.2134752f*x;
    float tc = fminf(t, 126.f);
    float e = __builtin_amdgcn_exp2f(tc);
    float l = __builtin_amdgcn_logf(1.f + e);
    float r = l*0.13862944f;
    return (t > 126.f) ? x : r;
}

// ---------------- prep: w2T[hout*64+hin] = bf16(rW2[hin][hout])
__global__ void k_prep2(const float* __restrict__ rW2, unsigned short* __restrict__ w2T){
    int idx = blockIdx.x*256 + threadIdx.x;     // [0,4096)
    int hout = idx >> 6, hin = idx & 63;
    w2T[idx] = f2bf(rW2[hin*64 + hout]);
}

// ---------------- tmp GEMM bf16 MFMA: Tg[m][s*4096 + j*64 + h] = (f_s[m] @ rWo[h][j][:]) * mask*c
// layer 0 (feat != null): f_s rows computed on the fly from the linear encoders.
__global__ __launch_bounds__(256,2) void k_tmpB(
    const unsigned short* __restrict__ fb, const unsigned short* __restrict__ fc,
    const float* __restrict__ feat,
    const float* __restrict__ Wb, const float* __restrict__ bb,
    const float* __restrict__ Wc, const float* __restrict__ bc,
    const float* __restrict__ mask, const float* __restrict__ rWo,
    unsigned short* __restrict__ Tg)
{
    __shared__ unsigned short sm[18432];   // As[128*72] | Bs[128*72]; Cs overlays all
    __shared__ float msk[128];
    __shared__ float featS[128*8];
    __shared__ float WbS[7*64];
    __shared__ float bbS[64], WcS[64], bcS[64];
    unsigned short* As = sm;
    unsigned short* Bs = sm + 9216;
    unsigned short* Cs = sm;

    int tid = threadIdx.x;
    int m0 = blockIdx.x*128, n0 = blockIdx.y*128, s = blockIdx.z;
    int lane = tid & 63, w = tid >> 6, q = lane >> 4, l15 = lane & 15;
    int wm = w & 1, wn = w >> 1;

    if (feat){
        // stage encoder inputs
        #pragma unroll
        for (int it = 0; it < 4; it++){
            int idx = tid + it*256;            // 1024 floats
            featS[idx] = feat[(size_t)m0*8 + idx];
        }
        for (int i = tid; i < 448; i += 256) WbS[i] = Wb[i];   // 7x64, strided
        if (tid < 64){ bbS[tid] = bb[tid]; WcS[tid] = Wc[tid]; bcS[tid] = bc[tid]; }
        __syncthreads();
        #pragma unroll
        for (int it = 0; it < 32; it++){
            int idx = tid + it*256;            // 8192
            int r = idx >> 6, e = idx & 63;
            float acc;
            if (s == 0){
                acc = bbS[e];
                #pragma unroll
                for (int c = 0; c < 7; c++) acc += featS[r*8+c]*WbS[c*64+e];
            } else {
                acc = bcS[e] + featS[r*8+7]*WcS[e];
            }
            As[r*72 + e] = f2bf(acc);
        }
    } else {
        const unsigned short* f = s ? fc : fb;
        #pragma unroll
        for (int it = 0; it < 4; it++){
            int idx = tid + it*256;            // 1024 uint4
            int r = idx >> 3, c8 = idx & 7;
            *(uint4*)(As + r*72 + c8*8) = *(const uint4*)(f + (size_t)(m0 + r)*64 + c8*8);
        }
    }
    // B-staging: row r -> n = n0+r = j*64+h -> rWo[(h*64+j)*64 + i], fp32->bf16
    #pragma unroll
    for (int it = 0; it < 8; it++){
        int idx = tid + it*256;                // 2048 float4
        int r = idx >> 4, c4 = idx & 15;
        int n = n0 + r;
        int j = n >> 6, h = n & 63;
        float4 v = *(const float4*)(rWo + (size_t)(h*64 + j)*64 + c4*4);
        ushort4 o; o.x = f2bf(v.x); o.y = f2bf(v.y); o.z = f2bf(v.z); o.w = f2bf(v.w);
        *(ushort4*)(Bs + r*72 + c4*4) = o;
    }
    if (tid < 128) msk[tid] = mask[m0 + tid] * 0.07216878364870322f;
    __syncthreads();

    f32x4 acc[16];
    #pragma unroll
    for (int i = 0; i < 16; i++) acc[i] = (f32x4){0.f,0.f,0.f,0.f};
    #pragma unroll
    for (int kc = 0; kc < 2; kc++){
        bf16x8 af[4];
        #pragma unroll
        for (int mt = 0; mt < 4; mt++)
            af[mt] = *(const bf16x8*)(As + (wm*64 + mt*16 + l15)*72 + kc*32 + q*8);
        #pragma unroll
        for (int nt = 0; nt < 4; nt++){
            bf16x8 bf_ = *(const bf16x8*)(Bs + (wn*64 + nt*16 + l15)*72 + kc*32 + q*8);
            #pragma unroll
            for (int mt = 0; mt < 4; mt++)
                acc[mt*4+nt] = __builtin_amdgcn_mfma_f32_16x16x32_bf16(af[mt], bf_, acc[mt*4+nt], 0, 0, 0);
        }
    }
    __syncthreads();   // all As/Bs reads done -> overlay Cs
    #pragma unroll
    for (int mt = 0; mt < 4; mt++)
        #pragma unroll
        for (int nt = 0; nt < 4; nt++)
            #pragma unroll
            for (int e = 0; e < 4; e++){
                int row2 = mt*16 + q*4 + e;
                float v = acc[mt*4+nt][e] * msk[wm*64 + row2];
                Cs[w*4608 + row2*72 + nt*16 + l15] = f2bf(v);
            }
    __syncthreads();
    #pragma unroll
    for (int it = 0; it < 8; it++){
        int flat = lane + it*64;               // [0,512)
        int rr = flat >> 3, c8 = flat & 7;
        uint4 v = *(const uint4*)(Cs + w*4608 + rr*72 + c8*8);
        size_t dst = (size_t)(m0 + wm*64 + rr)*8192 + s*4096 + n0 + wn*64 + c8*8;
        *(uint4*)(Tg + dst) = v;
    }
}

// ---------------- radial MLP -> R[z][b][a][h] bf16 (b-major for contract coalescing)
// h2 B-fragments (rW2^T) live in registers; no per-block transpose.
__global__ __launch_bounds__(256,3) void k_radial(
    const float* __restrict__ geom,
    const float* __restrict__ rW1, const float* __restrict__ rb1,
    const unsigned short* __restrict__ w2T, const float* __restrict__ rb2,
    unsigned short* __restrict__ Rc)
{
    __shared__ unsigned short H[256*72];      // h1, then R tile (36.9 KB)
    __shared__ float W1s[NBAS*64];            // 10.2 KB
    __shared__ float rb1s[64], rb2s[64];
    __shared__ float pc0s[256], pc1s[256];
    __shared__ int po0s[256], po1s[256];
    __shared__ float gx[16],gy[16],gz[16],hx[16],hy[16],hz[16];

    int tid = threadIdx.x;
    int z = blockIdx.x;
    int ta = blockIdx.y % 12, tb = blockIdx.y / 12;
    int a0 = ta*16, b0 = tb*16;
    int lane = tid & 63, w = tid >> 6, q = lane >> 4, l15 = lane & 15;

    // B-fragments from global (coalesced: 16 rows x 64B per load)
    bf16x8 bfr[2][4];
    #pragma unroll
    for (int kc = 0; kc < 2; kc++)
        #pragma unroll
        for (int nt = 0; nt < 4; nt++)
            bfr[kc][nt] = *(const bf16x8*)(w2T + (nt*16 + l15)*64 + kc*32 + q*8);

    #pragma unroll
    for (int i = 0; i < 10; i++) W1s[tid + i*256] = rW1[tid + i*256];
    if (tid < 64){ rb1s[tid] = rb1[tid]; rb2s[tid] = rb2[tid]; }
    if (tid < 16){
        int g = (z*NATOMS + a0 + tid)*3;
        gx[tid] = geom[g]; gy[tid] = geom[g+1]; gz[tid] = geom[g+2];
    } else if (tid < 32){
        int t2 = tid - 16;
        int g = (z*NATOMS + b0 + t2)*3;
        hx[t2] = geom[g]; hy[t2] = geom[g+1]; hz[t2] = geom[g+2];
    }
    __syncthreads();

    {   // pair coefficients (2-sparse cosine basis)
        int a_l = tid >> 4, b_l = tid & 15;
        float dx = gx[a_l]-hx[b_l], dy = gy[a_l]-hy[b_l], dz = gz[a_l]-hz[b_l];
        float r = sqrtf(dx*dx + dy*dy + dz*dz);
        float u = r * 3.9f;
        int k0 = (int)u;
        float fr = u - (float)k0;
        float cs = __cosf(fr * 1.57079632679489662f);
        float c0 = cs*cs, c1 = 1.f - c0;
        if (k0   >= NBAS) c0 = 0.f;
        if (k0+1 >= NBAS) c1 = 0.f;
        pc0s[tid] = c0; pc1s[tid] = c1;
        po0s[tid] = min(k0, NBAS-1)*64;
        po1s[tid] = min(k0+1, NBAS-1)*64;
    }
    __syncthreads();

    float bias1 = rb1s[lane];
    #pragma unroll 8
    for (int i = 0; i < 64; i++){
        int p = w*64 + i;
        float c0 = pc0s[p], c1 = pc1s[p];
        int o0 = po0s[p], o1 = po1s[p];
        float pre = bias1 + c0*W1s[o0 + lane] + c1*W1s[o1 + lane];
        H[p*72 + lane] = f2bf(sspf(pre));
    }
    __syncthreads();

    f32x4 acc[16];
    #pragma unroll
    for (int i = 0; i < 16; i++) acc[i] = (f32x4){0.f,0.f,0.f,0.f};
    #pragma unroll
    for (int kc = 0; kc < 2; kc++){
        bf16x8 af[4];
        #pragma unroll
        for (int mt = 0; mt < 4; mt++)
            af[mt] = *(const bf16x8*)(H + ((w*4 + mt)*16 + l15)*72 + kc*32 + q*8);
        #pragma unroll
        for (int nt = 0; nt < 4; nt++){
            #pragma unroll
            for (int mt = 0; mt < 4; mt++)
                acc[mt*4+nt] = __builtin_amdgcn_mfma_f32_16x16x32_bf16(af[mt], bfr[kc][nt], acc[mt*4+nt], 0, 0, 0);
        }
    }
    __syncthreads();
    #pragma unroll
    for (int mt = 0; mt < 4; mt++)
        #pragma unroll
        for (int nt = 0; nt < 4; nt++){
            float b2 = rb2s[nt*16 + l15];
            #pragma unroll
            for (int e = 0; e < 4; e++){
                int p = (w*4 + mt)*16 + q*4 + e;
                H[p*72 + nt*16 + l15] = f2bf(sspf(acc[mt*4+nt][e] + b2));
            }
        }
    __syncthreads();
    // copy R tile out b-major: R[z][b0+b_l][a0+a_l][h]
    #pragma unroll
    for (int it = 0; it < 8; it++){
        int e = tid + it*256;                  // [0,2048) uint4s
        int a_l = e >> 7, b_l = (e >> 3) & 15, h0 = (e & 7)*8;
        uint4 v = *(const uint4*)(H + (a_l*16 + b_l)*72 + h0);
        size_t dst = ((size_t)(z*NATOMS + b0 + b_l)*NATOMS + a0 + a_l)*64 + h0;
        *(uint4*)(Rc + dst) = v;
    }
}

// ---------------- contraction: part[z][kc][a][j2] (bf16) = sum_{b in chunk} R[z][b]·T[z][b]
// R b-major: per-b A tile (192x64) fully contiguous; single LDS buffer + register prefetch.
// Epilogue stages C through LDS so every 128B line is written once, contiguously.
__global__ __launch_bounds__(256,2) void k_contract(
    const unsigned short* __restrict__ Rc, const unsigned short* __restrict__ Tc,
    unsigned short* __restrict__ part)
{
    __shared__ unsigned short smA[192*72];   // 27648 B
    __shared__ unsigned short smB[128*72];   // 18432 B

    int tid = threadIdx.x;
    int zl = blockIdx.x, kc = blockIdx.y;
    int lane = tid & 63, w = tid >> 6, q = lane >> 4, l15 = lane & 15;
    int a_r = tid >> 3, c8 = tid & 7;        // staging coords

    f32x4 acc[24];
    #pragma unroll
    for (int i = 0; i < 24; i++) acc[i] = (f32x4){0.f,0.f,0.f,0.f};

    const size_t Rbase = (size_t)zl*NATOMS*NATOMS*64;
    const size_t Tbase = (size_t)zl*NATOMS*8192;

    uint4 ra[6], rb[4];
    {   // prefetch first b
        const unsigned short* Ab = Rc + Rbase + (size_t)(kc*6)*NATOMS*64;
        #pragma unroll
        for (int r = 0; r < 6; r++) ra[r] = *(const uint4*)(Ab + (size_t)(a_r + 32*r)*64 + c8*8);
        const unsigned short* Bb = Tc + Tbase + (size_t)(kc*6)*8192;
        #pragma unroll
        for (int r = 0; r < 4; r++) rb[r] = *(const uint4*)(Bb + (size_t)(a_r + 32*r)*64 + c8*8);
    }
    for (int i = 0; i < 6; i++){
        __syncthreads();   // previous MFMA LDS reads complete
        #pragma unroll
        for (int r = 0; r < 6; r++) *(uint4*)(smA + (a_r + 32*r)*72 + c8*8) = ra[r];
        #pragma unroll
        for (int r = 0; r < 4; r++) *(uint4*)(smB + (a_r + 32*r)*72 + c8*8) = rb[r];
        if (i < 5){
            int b = kc*6 + i + 1;
            const unsigned short* Ab = Rc + Rbase + (size_t)b*NATOMS*64;
            #pragma unroll
            for (int r = 0; r < 6; r++) ra[r] = *(const uint4*)(Ab + (size_t)(a_r + 32*r)*64 + c8*8);
            const unsigned short* Bb = Tc + Tbase + (size_t)b*8192;
            #pragma unroll
            for (int r = 0; r < 4; r++) rb[r] = *(const uint4*)(Bb + (size_t)(a_r + 32*r)*64 + c8*8);
        }
        __syncthreads();   // LDS tile ready
        #pragma unroll
        for (int kq = 0; kq < 2; kq++){
            bf16x8 af[3];
            #pragma unroll
            for (int mt = 0; mt < 3; mt++)
                af[mt] = *(const bf16x8*)(smA + (w*48 + mt*16 + l15)*72 + kq*32 + q*8);
            #pragma unroll
            for (int nt = 0; nt < 8; nt++){
                bf16x8 bf_ = *(const bf16x8*)(smB + (nt*16 + l15)*72 + kq*32 + q*8);
                #pragma unroll
                for (int mt = 0; mt < 3; mt++)
                    acc[mt*8+nt] = __builtin_amdgcn_mfma_f32_16x16x32_bf16(af[mt], bf_, acc[mt*8+nt], 0, 0, 0);
            }
        }
    }
    // ---- epilogue: stage C (192x128 bf16) through LDS in two 96-row halves,
    // then drain with fully-contiguous uint4 stores (whole 128B lines, written once).
    unsigned short* stg = smA;               // reuse, row stride 136 shorts (<=2-way banks)
    #pragma unroll
    for (int half = 0; half < 2; half++){
        __syncthreads();
        if ((w >> 1) == half){
            int wl = w & 1;
            #pragma unroll
            for (int mt = 0; mt < 3; mt++)
                #pragma unroll
                for (int nt = 0; nt < 8; nt++)
                    #pragma unroll
                    for (int e = 0; e < 4; e++){
                        int row = wl*48 + mt*16 + q*4 + e;      // [0,96)
                        stg[row*136 + nt*16 + l15] = f2bf(acc[mt*8+nt][e]);
                    }
        }
        __syncthreads();
        unsigned short* gdst = part + ((size_t)(zl*NKC + kc)*NATOMS + half*96)*128;
        #pragma unroll
        for (int it = 0; it < 6; it++){
            int flat = tid + it*256;          // [0,1536) uint4s
            int row = flat >> 4, cc = flat & 15;
            uint4 v = *(const uint4*)(stg + row*136 + cc*8);
            *(uint4*)(gdst + row*128 + cc*8) = v;
        }
    }
}

// ---------------- reduce partials + sp + mask -> bf16 next features
__global__ void k_reduceB(const unsigned short* __restrict__ part, const float* __restrict__ mask,
                          unsigned short* __restrict__ fb, unsigned short* __restrict__ fc){
    int zl = blockIdx.y;
    int idx = blockIdx.x*256 + threadIdx.x;    // [0, 24576)
    int a = idx >> 7, j2 = idx & 127;
    const unsigned short* p = part + ((size_t)(zl*NKC)*NATOMS + a)*128 + j2;
    float s = 0.f;
    #pragma unroll
    for (int c = 0; c < NKC; c++) s += bf2f(p[(size_t)c*NATOMS*128]);
    int rowg = zl*NATOMS + a;
    float v = spf_act(s) * mask[rowg];
    if (j2 < 64) fb[rowg*64 + j2] = f2bf(v);
    else         fc[rowg*64 + j2 - 64] = f2bf(v);
}

// ---------------- fused head: h1 + BN1 + leaky + h2 + BN2 + leaky + mask -> y2
__global__ __launch_bounds__(256) void k_head(
    const unsigned short* __restrict__ fbio, const unsigned short* __restrict__ fch,
    const float* __restrict__ fW1, const float* __restrict__ fb1,
    const float* __restrict__ fW2, const float* __restrict__ fb2,
    const float* __restrict__ mask, float* __restrict__ y2)
{
    __shared__ float X[2048];
    __shared__ float red[16];
    __shared__ float stats[2];
    int a = blockIdx.x, tid = threadIdx.x;
    int lane = tid & 63, w = tid >> 6;

    #pragma unroll
    for (int i = 0; i < 8; i++){
        int idx = tid + i*256; int z = idx >> 7, c = idx & 127;
        int row = z*NATOMS + a;
        X[idx] = (c < 64) ? bf2f(fbio[row*64 + c]) : bf2f(fch[row*64 + c - 64]);
    }
    __syncthreads();
    // h1: 2 float4 outputs per thread
    f32x4 v[2]; float s = 0.f, ss = 0.f;
    #pragma unroll
    for (int i = 0; i < 2; i++){
        int idx4 = tid + i*256; int z = idx4 >> 5, k4 = (idx4 & 31)*4;
        f32x4 acc = { fb1[k4], fb1[k4+1], fb1[k4+2], fb1[k4+3] };
        #pragma unroll 4
        for (int c = 0; c < 128; c++){
            float xv = X[z*128 + c];
            float4 wv = *(const float4*)(fW1 + (size_t)c*128 + k4);
            acc[0] += xv*wv.x; acc[1] += xv*wv.y; acc[2] += xv*wv.z; acc[3] += xv*wv.w;
        }
        v[i] = acc;
        s += acc[0]+acc[1]+acc[2]+acc[3];
        ss += acc[0]*acc[0]+acc[1]*acc[1]+acc[2]*acc[2]+acc[3]*acc[3];
    }
    for (int off = 32; off; off >>= 1){ s += __shfl_down(s, off); ss += __shfl_down(ss, off); }
    if (!lane){ red[w] = s; red[8+w] = ss; }
    __syncthreads();
    if (!tid){
        float S = red[0]+red[1]+red[2]+red[3];
        float SS = red[8]+red[9]+red[10]+red[11];
        float m = S*(1.f/2048.f), var = SS*(1.f/2048.f) - m*m;
        stats[0] = m; stats[1] = rsqrtf(var + 1e-5f);
    }
    __syncthreads();
    float m1 = stats[0], inv1 = stats[1];
    #pragma unroll
    for (int i = 0; i < 2; i++){
        int idx4 = tid + i*256;
        f32x4 t;
        #pragma unroll
        for (int e = 0; e < 4; e++){
            float x = (v[i][e]-m1)*inv1;
            t[e] = (x > 0.f) ? x : 0.2f*x;
        }
        *(f32x4*)(X + idx4*4) = t;
    }
    __syncthreads();
    // h2: 2 outputs per thread
    float u[2]; s = 0.f; ss = 0.f;
    #pragma unroll
    for (int i = 0; i < 2; i++){
        int idx = tid + i*256; int z = idx >> 5, j = idx & 31;
        float acc = fb2[j];
        #pragma unroll 8
        for (int k = 0; k < 128; k++) acc += X[z*128 + k]*fW2[k*32 + j];
        u[i] = acc; s += acc; ss += acc*acc;
    }
    for (int off = 32; off; off >>= 1){ s += __shfl_down(s, off); ss += __shfl_down(ss, off); }
    if (!lane){ red[w] = s; red[8+w] = ss; }
    __syncthreads();
    if (!tid){
        float S = red[0]+red[1]+red[2]+red[3];
        float SS = red[8]+red[9]+red[10]+red[11];
        float m = S*(1.f/512.f), var = SS*(1.f/512.f) - m*m;
        stats[0] = m; stats[1] = rsqrtf(var + 1e-5f);
    }
    __syncthreads();
    float m2 = stats[0], inv2 = stats[1];
    #pragma unroll
    for (int i = 0; i < 2; i++){
        int idx = tid + i*256; int z = idx >> 5, j = idx & 31;
        float x = (u[i]-m2)*inv2;
        x = (x > 0.f) ? x : 0.2f*x;
        y2[(size_t)(z*NATOMS + a)*32 + j] = x * mask[z*NATOMS + a];
    }
}

// ---------------- out[z,j] = sum_a y2[z,a,j]
__global__ void k_sum(const float* __restrict__ y2, float* __restrict__ out){
    int e = blockIdx.x;           // 512 outputs
    int z = e >> 5, jj = e & 31;
    int tid = threadIdx.x;        // 64
    float s = 0.f;
    for (int a = tid; a < NATOMS; a += 64) s += y2[(z*NATOMS + a)*32 + jj];
    for (int off = 32; off; off >>= 1) s += __shfl_down(s, off);
    if (!tid) out[e] = s;
}

extern "C" void kernel_launch(void* const* d_in, const int* in_sizes, int n_in,
                              void* d_out, int out_size, void* d_ws, size_t ws_size,
                              hipStream_t stream){
    const float* features = (const float*)d_in[0];
    const float* geometry = (const float*)d_in[1];
    const float* mask     = (const float*)d_in[2];
    const float* W_bio    = (const float*)d_in[3];
    const float* b_bio    = (const float*)d_in[4];
    const float* W_ch     = (const float*)d_in[5];
    const float* b_ch     = (const float*)d_in[6];
    const float* rW1[2] = {(const float*)d_in[7],  (const float*)d_in[12]};
    const float* rb1[2] = {(const float*)d_in[8],  (const float*)d_in[13]};
    const float* rW2[2] = {(const float*)d_in[9],  (const float*)d_in[14]};
    const float* rb2[2] = {(const float*)d_in[10], (const float*)d_in[15]};
    const float* rWo[2] = {(const float*)d_in[11], (const float*)d_in[16]};
    const float* fW1 = (const float*)d_in[17];
    const float* fb1 = (const float*)d_in[18];
    const float* fW2 = (const float*)d_in[19];
    const float* fb2 = (const float*)d_in[20];

    char* ws = (char*)d_ws;
    unsigned short* fAb = (unsigned short*)ws;   ws += (size_t)ZA*64*2;
    unsigned short* fAc = (unsigned short*)ws;   ws += (size_t)ZA*64*2;
    unsigned short* fBb = (unsigned short*)ws;   ws += (size_t)ZA*64*2;
    unsigned short* fBc = (unsigned short*)ws;   ws += (size_t)ZA*64*2;
    unsigned short* w2T = (unsigned short*)ws;   ws += (size_t)4096*2;
    unsigned short* Tg = (unsigned short*)ws;    ws += (size_t)ZA*8192*2;            // 50.3 MB
    unsigned short* Rc = (unsigned short*)ws;    ws += (size_t)ZB*NATOMS*NATOMS*64*2; // 75.5 MB
    unsigned short* part = (unsigned short*)ws;  ws += (size_t)ZB*NKC*NATOMS*128*2;   // 25.2 MB
    float* y2 = (float*)ws;                      ws += (size_t)ZA*32*4;

    dim3 gt(24, 32, 2);
    dim3 gr(ZB, 144);
    dim3 gc(ZB, NKC);
    dim3 gd(96, ZB);
    // layer 0 (encode fused into tmpB)
    k_prep2<<<16, 256, 0, stream>>>(rW2[0], w2T);
    k_tmpB<<<gt, 256, 0, stream>>>(nullptr, nullptr, features, W_bio, b_bio, W_ch, b_ch,
                                   mask, rWo[0], Tg);
    k_radial<<<gr, 256, 0, stream>>>(geometry, rW1[0], rb1[0], w2T, rb2[0], Rc);
    k_contract<<<gc, 256, 0, stream>>>(Rc, Tg, part);
    k_reduceB<<<gd, 256, 0, stream>>>(part, mask, fAb, fAc);
    // layer 1
    k_prep2<<<16, 256, 0, stream>>>(rW2[1], w2T);
    k_tmpB<<<gt, 256, 0, stream>>>(fAb, fAc, nullptr, W_bio, b_bio, W_ch, b_ch,
                                   mask, rWo[1], Tg);
    k_radial<<<gr, 256, 0, stream>>>(geometry, rW1[1], rb1[1], w2T, rb2[1], Rc);
    k_contract<<<gc, 256, 0, stream>>>(Rc, Tg, part);
    k_reduceB<<<gd, 256, 0, stream>>>(part, mask, fBb, fBc);
    // fused head + final sum
    k_head<<<NATOMS, 256, 0, stream>>>(fBb, fBc, fW1, fb1, fW2, fb2, mask, y2);
    k_sum<<<512, 64, 0, stream>>>(y2, (float*)d_out);
}

// Round 10
// 295.911 us; speedup vs baseline: 1.2865x; 1.2153x over previous
//
#include <hip/hip_runtime.h>
#include <math.h>

#define ZB 16
#define NATOMS 192
#define NBAS 40
#define ZA (ZB*NATOMS)       // 3072
#define NKC 32               // K-chunks in contraction

typedef __attribute__((ext_vector_type(4))) float f32x4;
typedef __attribute__((ext_vector_type(8))) short bf16x8;

__device__ __forceinline__ unsigned short f2bf(float x){
    union { float f; unsigned u; } v; v.f = x;
    unsigned r = v.u + 0x7FFFu + ((v.u >> 16) & 1u);
    return (unsigned short)(r >> 16);
}
__device__ __forceinline__ float bf2f(unsigned short u){
    union { unsigned u; float f; } v; v.u = ((unsigned)u) << 16; return v.f;
}
// ssp(x) = softplus(5x)/5 - ln2/5 via hw exp2/log2
__device__ __forceinline__ float sspf(float x){
    float t = 7.2134752f*x;
    float tc = fminf(t, 126.f);
    float e = __builtin_amdgcn_exp2f(tc);
    float l = __builtin_amdgcn_logf(1.f + e);   // log2
    float r = fmaf(l, 0.13862944f, -0.13862944f);
    return (t > 126.f) ? (x - 0.13862944f) : r;
}
__device__ __forceinline__ float spf_act(float x){
    float t = 7.2134752f*x;
    float tc = fminf(t, 126.f);
    float e = __builtin_amdgcn_exp2f(tc);
    float l = __builtin_amdgcn_logf(1.f + e);
    float r = l*0.13862944f;
    return (t > 126.f) ? x : r;
}

// ---------------- prep: w2T[hout*64+hin] = bf16(rW2[hin][hout])
__global__ void k_prep2(const float* __restrict__ rW2, unsigned short* __restrict__ w2T){
    int idx = blockIdx.x*256 + threadIdx.x;     // [0,4096)
    int hout = idx >> 6, hin = idx & 63;
    w2T[idx] = f2bf(rW2[hin*64 + hout]);
}

// ---------------- tmp GEMM bf16 MFMA: Tg[m][s*4096 + j*64 + h] = (f_s[m] @ rWo[h][j][:]) * mask*c
// layer 0 (feat != null): f_s rows computed on the fly from the linear encoders.
__global__ __launch_bounds__(256,2) void k_tmpB(
    const unsigned short* __restrict__ fb, const unsigned short* __restrict__ fc,
    const float* __restrict__ feat,
    const float* __restrict__ Wb, const float* __restrict__ bb,
    const float* __restrict__ Wc, const float* __restrict__ bc,
    const float* __restrict__ mask, const float* __restrict__ rWo,
    unsigned short* __restrict__ Tg)
{
    __shared__ unsigned short sm[18432];   // As[128*72] | Bs[128*72]; Cs overlays all
    __shared__ float msk[128];
    __shared__ float featS[128*8];
    __shared__ float WbS[7*64];
    __shared__ float bbS[64], WcS[64], bcS[64];
    unsigned short* As = sm;
    unsigned short* Bs = sm + 9216;
    unsigned short* Cs = sm;

    int tid = threadIdx.x;
    int m0 = blockIdx.x*128, n0 = blockIdx.y*128, s = blockIdx.z;
    int lane = tid & 63, w = tid >> 6, q = lane >> 4, l15 = lane & 15;
    int wm = w & 1, wn = w >> 1;

    if (feat){
        #pragma unroll
        for (int it = 0; it < 4; it++){
            int idx = tid + it*256;            // 1024 floats
            featS[idx] = feat[(size_t)m0*8 + idx];
        }
        for (int i = tid; i < 448; i += 256) WbS[i] = Wb[i];   // 7x64, strided
        if (tid < 64){ bbS[tid] = bb[tid]; WcS[tid] = Wc[tid]; bcS[tid] = bc[tid]; }
        __syncthreads();
        #pragma unroll
        for (int it = 0; it < 32; it++){
            int idx = tid + it*256;            // 8192
            int r = idx >> 6, e = idx & 63;
            float acc;
            if (s == 0){
                acc = bbS[e];
                #pragma unroll
                for (int c = 0; c < 7; c++) acc += featS[r*8+c]*WbS[c*64+e];
            } else {
                acc = bcS[e] + featS[r*8+7]*WcS[e];
            }
            As[r*72 + e] = f2bf(acc);
        }
    } else {
        const unsigned short* f = s ? fc : fb;
        #pragma unroll
        for (int it = 0; it < 4; it++){
            int idx = tid + it*256;            // 1024 uint4
            int r = idx >> 3, c8 = idx & 7;
            *(uint4*)(As + r*72 + c8*8) = *(const uint4*)(f + (size_t)(m0 + r)*64 + c8*8);
        }
    }
    // B-staging: row r -> n = n0+r = j*64+h -> rWo[(h*64+j)*64 + i], fp32->bf16
    #pragma unroll
    for (int it = 0; it < 8; it++){
        int idx = tid + it*256;                // 2048 float4
        int r = idx >> 4, c4 = idx & 15;
        int n = n0 + r;
        int j = n >> 6, h = n & 63;
        float4 v = *(const float4*)(rWo + (size_t)(h*64 + j)*64 + c4*4);
        ushort4 o; o.x = f2bf(v.x); o.y = f2bf(v.y); o.z = f2bf(v.z); o.w = f2bf(v.w);
        *(ushort4*)(Bs + r*72 + c4*4) = o;
    }
    if (tid < 128) msk[tid] = mask[m0 + tid] * 0.07216878364870322f;
    __syncthreads();

    f32x4 acc[16];
    #pragma unroll
    for (int i = 0; i < 16; i++) acc[i] = (f32x4){0.f,0.f,0.f,0.f};
    #pragma unroll
    for (int kc = 0; kc < 2; kc++){
        bf16x8 af[4];
        #pragma unroll
        for (int mt = 0; mt < 4; mt++)
            af[mt] = *(const bf16x8*)(As + (wm*64 + mt*16 + l15)*72 + kc*32 + q*8);
        #pragma unroll
        for (int nt = 0; nt < 4; nt++){
            bf16x8 bf_ = *(const bf16x8*)(Bs + (wn*64 + nt*16 + l15)*72 + kc*32 + q*8);
            #pragma unroll
            for (int mt = 0; mt < 4; mt++)
                acc[mt*4+nt] = __builtin_amdgcn_mfma_f32_16x16x32_bf16(af[mt], bf_, acc[mt*4+nt], 0, 0, 0);
        }
    }
    __syncthreads();   // all As/Bs reads done -> overlay Cs
    #pragma unroll
    for (int mt = 0; mt < 4; mt++)
        #pragma unroll
        for (int nt = 0; nt < 4; nt++)
            #pragma unroll
            for (int e = 0; e < 4; e++){
                int row2 = mt*16 + q*4 + e;
                float v = acc[mt*4+nt][e] * msk[wm*64 + row2];
                Cs[w*4608 + row2*72 + nt*16 + l15] = f2bf(v);
            }
    __syncthreads();
    #pragma unroll
    for (int it = 0; it < 8; it++){
        int flat = lane + it*64;               // [0,512)
        int rr = flat >> 3, c8 = flat & 7;
        uint4 v = *(const uint4*)(Cs + w*4608 + rr*72 + c8*8);
        size_t dst = (size_t)(m0 + wm*64 + rr)*8192 + s*4096 + n0 + wn*64 + c8*8;
        *(uint4*)(Tg + dst) = v;
    }
}

// ---------------- FUSED radial + contraction. Grid (ZB, NKC).
// Per block (z, kc): for each b in kc's 6: compute R rows on the fly (wave w owns
// rows w*48..+48 end-to-end: coeffs -> h1 -> h2 MFMA -> ssp -> R in LDS -> contraction
// MFMA). Only cross-wave dependency is the Tg B-tile (double-buffered, 1 barrier/b).
__global__ __launch_bounds__(256,2) void k_fused(
    const float* __restrict__ geom,
    const float* __restrict__ rW1, const float* __restrict__ rb1,
    const unsigned short* __restrict__ w2T, const float* __restrict__ rb2,
    const unsigned short* __restrict__ Tc,
    unsigned short* __restrict__ part)
{
    __shared__ unsigned short smH[192*72];      // 27648 B: H1 -> R -> epilogue staging
    __shared__ unsigned short smB[2][128*72];   // 36864 B: Tg tile double buffer
    __shared__ float W1s[NBAS*64];              // 10240 B
    __shared__ float rb1s[64], rb2s[64];
    __shared__ float pc0s[192], pc1s[192];
    __shared__ int po0s[192], po1s[192];

    int tid = threadIdx.x;
    int z = blockIdx.x, kc = blockIdx.y;
    int lane = tid & 63, w = tid >> 6, q = lane >> 4, l15 = lane & 15;
    int a_r = tid >> 3, c8 = tid & 7;

    #pragma unroll
    for (int i = 0; i < 10; i++) W1s[tid + i*256] = rW1[tid + i*256];
    if (tid < 64){ rb1s[tid] = rb1[tid]; rb2s[tid] = rb2[tid]; }

    // rW2^T fragments in registers (verified layout from k_radial)
    bf16x8 bfr[2][4];
    #pragma unroll
    for (int kq = 0; kq < 2; kq++)
        #pragma unroll
        for (int nt = 0; nt < 4; nt++)
            bfr[kq][nt] = *(const bf16x8*)(w2T + (nt*16 + l15)*64 + kq*32 + q*8);

    // this wave's a-row geometry (lanes 0..47 active)
    int al = w*48 + ((lane < 48) ? lane : 47);
    const float* gp = geom + (size_t)(z*NATOMS + al)*3;
    float gax = gp[0], gay = gp[1], gaz = gp[2];

    const size_t Tbase = (size_t)z*NATOMS*8192;
    uint4 rbv[4];
    {
        const unsigned short* Bb = Tc + Tbase + (size_t)(kc*6)*8192;
        #pragma unroll
        for (int r = 0; r < 4; r++) rbv[r] = *(const uint4*)(Bb + (size_t)(a_r + 32*r)*64 + c8*8);
    }

    f32x4 acc[24];
    #pragma unroll
    for (int i = 0; i < 24; i++) acc[i] = (f32x4){0.f,0.f,0.f,0.f};

    __syncthreads();           // W1s / biases staged
    float bias1 = rb1s[lane];

    for (int i = 0; i < 6; i++){
        int buf = i & 1;
        int b = kc*6 + i;
        // commit prefetched B tile to LDS (buf was last read 2 iters ago; barrier(i-1) covers)
        #pragma unroll
        for (int r = 0; r < 4; r++) *(uint4*)(smB[buf] + (a_r + 32*r)*72 + c8*8) = rbv[r];
        // prefetch next b
        if (i < 5){
            const unsigned short* Bb = Tc + Tbase + (size_t)(b+1)*8192;
            #pragma unroll
            for (int r = 0; r < 4; r++) rbv[r] = *(const uint4*)(Bb + (size_t)(a_r + 32*r)*64 + c8*8);
        }
        // pair coefficients for this wave's 48 rows (wave-local slice, no barrier needed)
        if (lane < 48){
            const float* gb = geom + (size_t)(z*NATOMS + b)*3;
            float dx = gax - gb[0], dy = gay - gb[1], dz = gaz - gb[2];
            float r = sqrtf(dx*dx + dy*dy + dz*dz);
            float u = r * 3.9f;
            int k0 = (int)u;
            float fr = u - (float)k0;
            float cs = __cosf(fr * 1.57079632679489662f);
            float c0 = cs*cs, c1 = 1.f - c0;
            if (k0   >= NBAS) c0 = 0.f;
            if (k0+1 >= NBAS) c1 = 0.f;
            int p = w*48 + lane;
            pc0s[p] = c0; pc1s[p] = c1;
            po0s[p] = min(k0, NBAS-1)*64;
            po1s[p] = min(k0+1, NBAS-1)*64;
        }
        __syncthreads();       // smB[buf] visible to all waves
        // h1 for rows w*48..+48 (lane = hin); wave-local rows -> in-order DS, no barrier
        #pragma unroll 8
        for (int ii = 0; ii < 48; ii++){
            int p = w*48 + ii;
            float c0 = pc0s[p], c1 = pc1s[p];
            int o0 = po0s[p], o1 = po1s[p];
            float pre = bias1 + c0*W1s[o0 + lane] + c1*W1s[o1 + lane];
            smH[p*72 + lane] = f2bf(sspf(pre));
        }
        // h2: R_pre = h1 @ rW2 (reads own rows; A-frag loads precede R overwrite in order)
        f32x4 hacc[12];
        #pragma unroll
        for (int t = 0; t < 12; t++) hacc[t] = (f32x4){0.f,0.f,0.f,0.f};
        #pragma unroll
        for (int kq = 0; kq < 2; kq++){
            bf16x8 haf[3];
            #pragma unroll
            for (int mt = 0; mt < 3; mt++)
                haf[mt] = *(const bf16x8*)(smH + (w*48 + mt*16 + l15)*72 + kq*32 + q*8);
            #pragma unroll
            for (int nt = 0; nt < 4; nt++)
                #pragma unroll
                for (int mt = 0; mt < 3; mt++)
                    hacc[mt*4+nt] = __builtin_amdgcn_mfma_f32_16x16x32_bf16(haf[mt], bfr[kq][nt], hacc[mt*4+nt], 0, 0, 0);
        }
        // R = ssp(R_pre + rb2) overwrites own rows of smH
        #pragma unroll
        for (int mt = 0; mt < 3; mt++)
            #pragma unroll
            for (int nt = 0; nt < 4; nt++){
                float b2 = rb2s[nt*16 + l15];
                #pragma unroll
                for (int e = 0; e < 4; e++){
                    int row = w*48 + mt*16 + q*4 + e;
                    smH[row*72 + nt*16 + l15] = f2bf(sspf(hacc[mt*4+nt][e] + b2));
                }
            }
        // contraction: acc += R(own rows) @ B-tile
        #pragma unroll
        for (int kq = 0; kq < 2; kq++){
            bf16x8 af[3];
            #pragma unroll
            for (int mt = 0; mt < 3; mt++)
                af[mt] = *(const bf16x8*)(smH + (w*48 + mt*16 + l15)*72 + kq*32 + q*8);
            #pragma unroll
            for (int nt = 0; nt < 8; nt++){
                bf16x8 bb = *(const bf16x8*)(smB[buf] + (nt*16 + l15)*72 + kq*32 + q*8);
                #pragma unroll
                for (int mt = 0; mt < 3; mt++)
                    acc[mt*8+nt] = __builtin_amdgcn_mfma_f32_16x16x32_bf16(af[mt], bb, acc[mt*8+nt], 0, 0, 0);
            }
        }
    }
    // epilogue: LDS-staged contiguous write of part tile (192x128 bf16)
    unsigned short* stg = smH;               // row stride 136 shorts
    #pragma unroll
    for (int half = 0; half < 2; half++){
        __syncthreads();
        if ((w >> 1) == half){
            int wl = w & 1;
            #pragma unroll
            for (int mt = 0; mt < 3; mt++)
                #pragma unroll
                for (int nt = 0; nt < 8; nt++)
                    #pragma unroll
                    for (int e = 0; e < 4; e++){
                        int row = wl*48 + mt*16 + q*4 + e;      // [0,96)
                        stg[row*136 + nt*16 + l15] = f2bf(acc[mt*8+nt][e]);
                    }
        }
        __syncthreads();
        unsigned short* gdst = part + ((size_t)(z*NKC + kc)*NATOMS + half*96)*128;
        #pragma unroll
        for (int it = 0; it < 6; it++){
            int flat = tid + it*256;          // [0,1536) uint4s
            int row = flat >> 4, cc = flat & 15;
            uint4 v = *(const uint4*)(stg + row*136 + cc*8);
            *(uint4*)(gdst + row*128 + cc*8) = v;
        }
    }
}

// ---------------- reduce partials + sp + mask -> bf16 next features
__global__ void k_reduceB(const unsigned short* __restrict__ part, const float* __restrict__ mask,
                          unsigned short* __restrict__ fb, unsigned short* __restrict__ fc){
    int zl = blockIdx.y;
    int idx = blockIdx.x*256 + threadIdx.x;    // [0, 24576)
    int a = idx >> 7, j2 = idx & 127;
    const unsigned short* p = part + ((size_t)(zl*NKC)*NATOMS + a)*128 + j2;
    float s = 0.f;
    #pragma unroll
    for (int c = 0; c < NKC; c++) s += bf2f(p[(size_t)c*NATOMS*128]);
    int rowg = zl*NATOMS + a;
    float v = spf_act(s) * mask[rowg];
    if (j2 < 64) fb[rowg*64 + j2] = f2bf(v);
    else         fc[rowg*64 + j2 - 64] = f2bf(v);
}

// ---------------- fused head: h1 + BN1 + leaky + h2 + BN2 + leaky + mask -> y2
__global__ __launch_bounds__(256) void k_head(
    const unsigned short* __restrict__ fbio, const unsigned short* __restrict__ fch,
    const float* __restrict__ fW1, const float* __restrict__ fb1,
    const float* __restrict__ fW2, const float* __restrict__ fb2,
    const float* __restrict__ mask, float* __restrict__ y2)
{
    __shared__ float X[2048];
    __shared__ float red[16];
    __shared__ float stats[2];
    int a = blockIdx.x, tid = threadIdx.x;
    int lane = tid & 63, w = tid >> 6;

    #pragma unroll
    for (int i = 0; i < 8; i++){
        int idx = tid + i*256; int z = idx >> 7, c = idx & 127;
        int row = z*NATOMS + a;
        X[idx] = (c < 64) ? bf2f(fbio[row*64 + c]) : bf2f(fch[row*64 + c - 64]);
    }
    __syncthreads();
    f32x4 v[2]; float s = 0.f, ss = 0.f;
    #pragma unroll
    for (int i = 0; i < 2; i++){
        int idx4 = tid + i*256; int z = idx4 >> 5, k4 = (idx4 & 31)*4;
        f32x4 acc = { fb1[k4], fb1[k4+1], fb1[k4+2], fb1[k4+3] };
        #pragma unroll 4
        for (int c = 0; c < 128; c++){
            float xv = X[z*128 + c];
            float4 wv = *(const float4*)(fW1 + (size_t)c*128 + k4);
            acc[0] += xv*wv.x; acc[1] += xv*wv.y; acc[2] += xv*wv.z; acc[3] += xv*wv.w;
        }
        v[i] = acc;
        s += acc[0]+acc[1]+acc[2]+acc[3];
        ss += acc[0]*acc[0]+acc[1]*acc[1]+acc[2]*acc[2]+acc[3]*acc[3];
    }
    for (int off = 32; off; off >>= 1){ s += __shfl_down(s, off); ss += __shfl_down(ss, off); }
    if (!lane){ red[w] = s; red[8+w] = ss; }
    __syncthreads();
    if (!tid){
        float S = red[0]+red[1]+red[2]+red[3];
        float SS = red[8]+red[9]+red[10]+red[11];
        float m = S*(1.f/2048.f), var = SS*(1.f/2048.f) - m*m;
        stats[0] = m; stats[1] = rsqrtf(var + 1e-5f);
    }
    __syncthreads();
    float m1 = stats[0], inv1 = stats[1];
    #pragma unroll
    for (int i = 0; i < 2; i++){
        int idx4 = tid + i*256;
        f32x4 t;
        #pragma unroll
        for (int e = 0; e < 4; e++){
            float x = (v[i][e]-m1)*inv1;
            t[e] = (x > 0.f) ? x : 0.2f*x;
        }
        *(f32x4*)(X + idx4*4) = t;
    }
    __syncthreads();
    float u[2]; s = 0.f; ss = 0.f;
    #pragma unroll
    for (int i = 0; i < 2; i++){
        int idx = tid + i*256; int z = idx >> 5, j = idx & 31;
        float acc = fb2[j];
        #pragma unroll 8
        for (int k = 0; k < 128; k++) acc += X[z*128 + k]*fW2[k*32 + j];
        u[i] = acc; s += acc; ss += acc*acc;
    }
    for (int off = 32; off; off >>= 1){ s += __shfl_down(s, off); ss += __shfl_down(ss, off); }
    if (!lane){ red[w] = s; red[8+w] = ss; }
    __syncthreads();
    if (!tid){
        float S = red[0]+red[1]+red[2]+red[3];
        float SS = red[8]+red[9]+red[10]+red[11];
        float m = S*(1.f/512.f), var = SS*(1.f/512.f) - m*m;
        stats[0] = m; stats[1] = rsqrtf(var + 1e-5f);
    }
    __syncthreads();
    float m2 = stats[0], inv2 = stats[1];
    #pragma unroll
    for (int i = 0; i < 2; i++){
        int idx = tid + i*256; int z = idx >> 5, j = idx & 31;
        float x = (u[i]-m2)*inv2;
        x = (x > 0.f) ? x : 0.2f*x;
        y2[(size_t)(z*NATOMS + a)*32 + j] = x * mask[z*NATOMS + a];
    }
}

// ---------------- out[z,j] = sum_a y2[z,a,j]
__global__ void k_sum(const float* __restrict__ y2, float* __restrict__ out){
    int e = blockIdx.x;           // 512 outputs
    int z = e >> 5, jj = e & 31;
    int tid = threadIdx.x;        // 64
    float s = 0.f;
    for (int a = tid; a < NATOMS; a += 64) s += y2[(z*NATOMS + a)*32 + jj];
    for (int off = 32; off; off >>= 1) s += __shfl_down(s, off);
    if (!tid) out[e] = s;
}

extern "C" void kernel_launch(void* const* d_in, const int* in_sizes, int n_in,
                              void* d_out, int out_size, void* d_ws, size_t ws_size,
                              hipStream_t stream){
    const float* features = (const float*)d_in[0];
    const float* geometry = (const float*)d_in[1];
    const float* mask     = (const float*)d_in[2];
    const float* W_bio    = (const float*)d_in[3];
    const float* b_bio    = (const float*)d_in[4];
    const float* W_ch     = (const float*)d_in[5];
    const float* b_ch     = (const float*)d_in[6];
    const float* rW1[2] = {(const float*)d_in[7],  (const float*)d_in[12]};
    const float* rb1[2] = {(const float*)d_in[8],  (const float*)d_in[13]};
    const float* rW2[2] = {(const float*)d_in[9],  (const float*)d_in[14]};
    const float* rb2[2] = {(const float*)d_in[10], (const float*)d_in[15]};
    const float* rWo[2] = {(const float*)d_in[11], (const float*)d_in[16]};
    const float* fW1 = (const float*)d_in[17];
    const float* fb1 = (const float*)d_in[18];
    const float* fW2 = (const float*)d_in[19];
    const float* fb2 = (const float*)d_in[20];

    char* ws = (char*)d_ws;
    unsigned short* fAb = (unsigned short*)ws;   ws += (size_t)ZA*64*2;
    unsigned short* fAc = (unsigned short*)ws;   ws += (size_t)ZA*64*2;
    unsigned short* fBb = (unsigned short*)ws;   ws += (size_t)ZA*64*2;
    unsigned short* fBc = (unsigned short*)ws;   ws += (size_t)ZA*64*2;
    unsigned short* w2T = (unsigned short*)ws;   ws += (size_t)4096*2;
    unsigned short* Tg = (unsigned short*)ws;    ws += (size_t)ZA*8192*2;            // 50.3 MB
    unsigned short* part = (unsigned short*)ws;  ws += (size_t)ZB*NKC*NATOMS*128*2;   // 25.2 MB
    float* y2 = (float*)ws;                      ws += (size_t)ZA*32*4;

    dim3 gt(24, 32, 2);
    dim3 gf(ZB, NKC);
    dim3 gd(96, ZB);
    // layer 0 (encode fused into tmpB)
    k_prep2<<<16, 256, 0, stream>>>(rW2[0], w2T);
    k_tmpB<<<gt, 256, 0, stream>>>(nullptr, nullptr, features, W_bio, b_bio, W_ch, b_ch,
                                   mask, rWo[0], Tg);
    k_fused<<<gf, 256, 0, stream>>>(geometry, rW1[0], rb1[0], w2T, rb2[0], Tg, part);
    k_reduceB<<<gd, 256, 0, stream>>>(part, mask, fAb, fAc);
    // layer 1
    k_prep2<<<16, 256, 0, stream>>>(rW2[1], w2T);
    k_tmpB<<<gt, 256, 0, stream>>>(fAb, fAc, nullptr, W_bio, b_bio, W_ch, b_ch,
                                   mask, rWo[1], Tg);
    k_fused<<<gf, 256, 0, stream>>>(geometry, rW1[1], rb1[1], w2T, rb2[1], Tg, part);
    k_reduceB<<<gd, 256, 0, stream>>>(part, mask, fBb, fBc);
    // fused head + final sum
    k_head<<<NATOMS, 256, 0, stream>>>(fBb, fBc, fW1, fb1, fW2, fb2, mask, y2);
    k_sum<<<512, 64, 0, stream>>>(y2, (float*)d_out);
}

// Round 11
// 280.131 us; speedup vs baseline: 1.3589x; 1.0563x over previous
//
#include <hip/hip_runtime.h>
#include <math.h>

#define ZB 16
#define NATOMS 192
#define NBAS 40
#define ZA (ZB*NATOMS)       // 3072
#define NKC 32               // K-chunks in contraction

typedef __attribute__((ext_vector_type(4))) float f32x4;
typedef __attribute__((ext_vector_type(8))) short bf16x8;

__device__ __forceinline__ unsigned short f2bf(float x){
    union { float f; unsigned u; } v; v.f = x;
    unsigned r = v.u + 0x7FFFu + ((v.u >> 16) & 1u);
    return (unsigned short)(r >> 16);
}
__device__ __forceinline__ float bf2f(unsigned short u){
    union { unsigned u; float f; } v; v.u = ((unsigned)u) << 16; return v.f;
}
// ssp(x) = softplus(5x)/5 - ln2/5 via hw exp2/log2
__device__ __forceinline__ float sspf(float x){
    float t = 7.2134752f*x;
    float tc = fminf(t, 126.f);
    float e = __builtin_amdgcn_exp2f(tc);
    float l = __builtin_amdgcn_logf(1.f + e);   // log2
    float r = fmaf(l, 0.13862944f, -0.13862944f);
    return (t > 126.f) ? (x - 0.13862944f) : r;
}
__device__ __forceinline__ float spf_act(float x){
    float t = 7.2134752f*x;
    float tc = fminf(t, 126.f);
    float e = __builtin_amdgcn_exp2f(tc);
    float l = __builtin_amdgcn_logf(1.f + e);
    float r = l*0.13862944f;
    return (t > 126.f) ? x : r;
}

// ---------------- prep: w2T[hout*64+hin] = bf16(rW2[hin][hout])
__global__ void k_prep2(const float* __restrict__ rW2, unsigned short* __restrict__ w2T){
    int idx = blockIdx.x*256 + threadIdx.x;     // [0,4096)
    int hout = idx >> 6, hin = idx & 63;
    w2T[idx] = f2bf(rW2[hin*64 + hout]);
}

// ---------------- tmp GEMM bf16 MFMA: Tg[m][s*4096 + j*64 + h] = (f_s[m] @ rWo[h][j][:]) * mask*c
// layer 0 (feat != null): f_s rows computed on the fly from the linear encoders.
__global__ __launch_bounds__(256,2) void k_tmpB(
    const unsigned short* __restrict__ fb, const unsigned short* __restrict__ fc,
    const float* __restrict__ feat,
    const float* __restrict__ Wb, const float* __restrict__ bb,
    const float* __restrict__ Wc, const float* __restrict__ bc,
    const float* __restrict__ mask, const float* __restrict__ rWo,
    unsigned short* __restrict__ Tg)
{
    __shared__ unsigned short sm[18432];   // As[128*72] | Bs[128*72]; Cs overlays all
    __shared__ float msk[128];
    __shared__ float featS[128*8];
    __shared__ float WbS[7*64];
    __shared__ float bbS[64], WcS[64], bcS[64];
    unsigned short* As = sm;
    unsigned short* Bs = sm + 9216;
    unsigned short* Cs = sm;

    int tid = threadIdx.x;
    int m0 = blockIdx.x*128, n0 = blockIdx.y*128, s = blockIdx.z;
    int lane = tid & 63, w = tid >> 6, q = lane >> 4, l15 = lane & 15;
    int wm = w & 1, wn = w >> 1;

    if (feat){
        #pragma unroll
        for (int it = 0; it < 4; it++){
            int idx = tid + it*256;            // 1024 floats
            featS[idx] = feat[(size_t)m0*8 + idx];
        }
        for (int i = tid; i < 448; i += 256) WbS[i] = Wb[i];   // 7x64, strided
        if (tid < 64){ bbS[tid] = bb[tid]; WcS[tid] = Wc[tid]; bcS[tid] = bc[tid]; }
        __syncthreads();
        #pragma unroll
        for (int it = 0; it < 32; it++){
            int idx = tid + it*256;            // 8192
            int r = idx >> 6, e = idx & 63;
            float acc;
            if (s == 0){
                acc = bbS[e];
                #pragma unroll
                for (int c = 0; c < 7; c++) acc += featS[r*8+c]*WbS[c*64+e];
            } else {
                acc = bcS[e] + featS[r*8+7]*WcS[e];
            }
            As[r*72 + e] = f2bf(acc);
        }
    } else {
        const unsigned short* f = s ? fc : fb;
        #pragma unroll
        for (int it = 0; it < 4; it++){
            int idx = tid + it*256;            // 1024 uint4
            int r = idx >> 3, c8 = idx & 7;
            *(uint4*)(As + r*72 + c8*8) = *(const uint4*)(f + (size_t)(m0 + r)*64 + c8*8);
        }
    }
    // B-staging: row r -> n = n0+r = j*64+h -> rWo[(h*64+j)*64 + i], fp32->bf16
    #pragma unroll
    for (int it = 0; it < 8; it++){
        int idx = tid + it*256;                // 2048 float4
        int r = idx >> 4, c4 = idx & 15;
        int n = n0 + r;
        int j = n >> 6, h = n & 63;
        float4 v = *(const float4*)(rWo + (size_t)(h*64 + j)*64 + c4*4);
        ushort4 o; o.x = f2bf(v.x); o.y = f2bf(v.y); o.z = f2bf(v.z); o.w = f2bf(v.w);
        *(ushort4*)(Bs + r*72 + c4*4) = o;
    }
    if (tid < 128) msk[tid] = mask[m0 + tid] * 0.07216878364870322f;
    __syncthreads();

    f32x4 acc[16];
    #pragma unroll
    for (int i = 0; i < 16; i++) acc[i] = (f32x4){0.f,0.f,0.f,0.f};
    #pragma unroll
    for (int kc = 0; kc < 2; kc++){
        bf16x8 af[4];
        #pragma unroll
        for (int mt = 0; mt < 4; mt++)
            af[mt] = *(const bf16x8*)(As + (wm*64 + mt*16 + l15)*72 + kc*32 + q*8);
        #pragma unroll
        for (int nt = 0; nt < 4; nt++){
            bf16x8 bf_ = *(const bf16x8*)(Bs + (wn*64 + nt*16 + l15)*72 + kc*32 + q*8);
            #pragma unroll
            for (int mt = 0; mt < 4; mt++)
                acc[mt*4+nt] = __builtin_amdgcn_mfma_f32_16x16x32_bf16(af[mt], bf_, acc[mt*4+nt], 0, 0, 0);
        }
    }
    __syncthreads();   // all As/Bs reads done -> overlay Cs
    #pragma unroll
    for (int mt = 0; mt < 4; mt++)
        #pragma unroll
        for (int nt = 0; nt < 4; nt++)
            #pragma unroll
            for (int e = 0; e < 4; e++){
                int row2 = mt*16 + q*4 + e;
                float v = acc[mt*4+nt][e] * msk[wm*64 + row2];
                Cs[w*4608 + row2*72 + nt*16 + l15] = f2bf(v);
            }
    __syncthreads();
    #pragma unroll
    for (int it = 0; it < 8; it++){
        int flat = lane + it*64;               // [0,512)
        int rr = flat >> 3, c8 = flat & 7;
        uint4 v = *(const uint4*)(Cs + w*4608 + rr*72 + c8*8);
        size_t dst = (size_t)(m0 + wm*64 + rr)*8192 + s*4096 + n0 + wn*64 + c8*8;
        *(uint4*)(Tg + dst) = v;
    }
}

// ---------------- FUSED radial + contraction. Grid (ZB, NKC).
// h1 is built directly into MFMA A-fragment registers (2x ds_read_b128 of bf16 W1
// rows per fragment) — no h1 LDS round-trip, no LDS coeff arrays. R still takes the
// required C->A LDS transpose. 1 barrier per b (Tg tile, double-buffered).
__global__ __launch_bounds__(256,2) void k_fused(
    const float* __restrict__ geom,
    const float* __restrict__ rW1, const float* __restrict__ rb1,
    const unsigned short* __restrict__ w2T, const float* __restrict__ rb2,
    const unsigned short* __restrict__ Tc,
    unsigned short* __restrict__ part)
{
    __shared__ unsigned short smH[192*72];      // 27648 B: R tile -> epilogue staging
    __shared__ unsigned short smB[2][128*72];   // 36864 B: Tg tile double buffer
    __shared__ unsigned short W1bf[NBAS*72];    // 5760 B, rows padded to 72
    __shared__ float rb2s[64];

    int tid = threadIdx.x;
    int z = blockIdx.x, kc = blockIdx.y;
    int lane = tid & 63, w = tid >> 6, q = lane >> 4, l15 = lane & 15;
    int a_r = tid >> 3, c8 = tid & 7;

    // stage W1 as bf16 (rows padded 72)
    #pragma unroll
    for (int i = 0; i < 10; i++){
        int idx = tid + i*256;                 // [0,2560)
        int r = idx >> 6, c = idx & 63;
        W1bf[r*72 + c] = f2bf(rW1[idx]);
    }
    if (tid < 64) rb2s[tid] = rb2[tid];

    // rW2^T fragments in registers (verified layout)
    bf16x8 bfr[2][4];
    #pragma unroll
    for (int kq = 0; kq < 2; kq++)
        #pragma unroll
        for (int nt = 0; nt < 4; nt++)
            bfr[kq][nt] = *(const bf16x8*)(w2T + (nt*16 + l15)*64 + kq*32 + q*8);

    // rb1 bias slice for this lane's k-positions: rb1[kq*32 + q*8 + j]
    float rb1v[2][8];
    #pragma unroll
    for (int kq = 0; kq < 2; kq++){
        float4 t0 = *(const float4*)(rb1 + kq*32 + q*8);
        float4 t1 = *(const float4*)(rb1 + kq*32 + q*8 + 4);
        rb1v[kq][0]=t0.x; rb1v[kq][1]=t0.y; rb1v[kq][2]=t0.z; rb1v[kq][3]=t0.w;
        rb1v[kq][4]=t1.x; rb1v[kq][5]=t1.y; rb1v[kq][6]=t1.z; rb1v[kq][7]=t1.w;
    }

    // this lane's 3 a-rows' geometry (rows w*48 + mt*16 + l15)
    float gaxr[3], gayr[3], gazr[3];
    #pragma unroll
    for (int mt = 0; mt < 3; mt++){
        int ar = w*48 + mt*16 + l15;
        const float* gp = geom + (size_t)(z*NATOMS + ar)*3;
        gaxr[mt] = gp[0]; gayr[mt] = gp[1]; gazr[mt] = gp[2];
    }

    const size_t Tbase = (size_t)z*NATOMS*8192;
    uint4 rbv[4];
    {
        const unsigned short* Bb = Tc + Tbase + (size_t)(kc*6)*8192;
        #pragma unroll
        for (int r = 0; r < 4; r++) rbv[r] = *(const uint4*)(Bb + (size_t)(a_r + 32*r)*64 + c8*8);
    }

    f32x4 acc[24];
    #pragma unroll
    for (int i = 0; i < 24; i++) acc[i] = (f32x4){0.f,0.f,0.f,0.f};

    __syncthreads();           // W1bf / rb2s staged

    for (int i = 0; i < 6; i++){
        int buf = i & 1;
        int b = kc*6 + i;
        // commit prefetched B tile to LDS (buf last read 2 iters ago; barrier(i-1) covers)
        #pragma unroll
        for (int r = 0; r < 4; r++) *(uint4*)(smB[buf] + (a_r + 32*r)*72 + c8*8) = rbv[r];
        // prefetch next b
        if (i < 5){
            const unsigned short* Bb = Tc + Tbase + (size_t)(b+1)*8192;
            #pragma unroll
            for (int r = 0; r < 4; r++) rbv[r] = *(const uint4*)(Bb + (size_t)(a_r + 32*r)*64 + c8*8);
        }
        // pair coefficients for this lane's 3 rows (registers, no LDS)
        const float* gb = geom + (size_t)(z*NATOMS + b)*3;
        float gbx = gb[0], gby = gb[1], gbz = gb[2];
        float c0r[3], c1r[3]; int o0r[3], o1r[3];
        #pragma unroll
        for (int mt = 0; mt < 3; mt++){
            float dx = gaxr[mt]-gbx, dy = gayr[mt]-gby, dz = gazr[mt]-gbz;
            float r = sqrtf(dx*dx + dy*dy + dz*dz);
            float u = r * 3.9f;
            int k0 = (int)u;
            float fr = u - (float)k0;
            float cs = __cosf(fr * 1.57079632679489662f);
            float c0 = cs*cs, c1 = 1.f - c0;
            if (k0   >= NBAS) c0 = 0.f;
            if (k0+1 >= NBAS) c1 = 0.f;
            c0r[mt] = c0; c1r[mt] = c1;
            o0r[mt] = min(k0, NBAS-1)*72;
            o1r[mt] = min(k0+1, NBAS-1)*72;
        }
        __syncthreads();       // smB[buf] visible to all waves
        // h2: R_pre = h1 @ rW2, with h1 A-frags built in registers
        f32x4 hacc[12];
        #pragma unroll
        for (int t = 0; t < 12; t++) hacc[t] = (f32x4){0.f,0.f,0.f,0.f};
        #pragma unroll
        for (int kq = 0; kq < 2; kq++){
            #pragma unroll
            for (int mt = 0; mt < 3; mt++){
                uint4 w0 = *(const uint4*)(W1bf + o0r[mt] + kq*32 + q*8);
                uint4 w1 = *(const uint4*)(W1bf + o1r[mt] + kq*32 + q*8);
                const unsigned* w0p = (const unsigned*)&w0;
                const unsigned* w1p = (const unsigned*)&w1;
                uint4 af_u;
                unsigned* ap = (unsigned*)&af_u;
                #pragma unroll
                for (int d = 0; d < 4; d++){
                    float a0 = bf2f((unsigned short)(w0p[d] & 0xffffu));
                    float a1 = bf2f((unsigned short)(w0p[d] >> 16));
                    float b0 = bf2f((unsigned short)(w1p[d] & 0xffffu));
                    float b1 = bf2f((unsigned short)(w1p[d] >> 16));
                    float v0 = fmaf(c1r[mt], b0, fmaf(c0r[mt], a0, rb1v[kq][2*d]));
                    float v1 = fmaf(c1r[mt], b1, fmaf(c0r[mt], a1, rb1v[kq][2*d+1]));
                    ap[d] = (unsigned)f2bf(sspf(v0)) | ((unsigned)f2bf(sspf(v1)) << 16);
                }
                bf16x8 af = *(bf16x8*)&af_u;
                #pragma unroll
                for (int nt = 0; nt < 4; nt++)
                    hacc[mt*4+nt] = __builtin_amdgcn_mfma_f32_16x16x32_bf16(af, bfr[kq][nt], hacc[mt*4+nt], 0, 0, 0);
            }
        }
        // R = ssp(R_pre + rb2) -> smH (own rows; wave-local in-order)
        #pragma unroll
        for (int mt = 0; mt < 3; mt++)
            #pragma unroll
            for (int nt = 0; nt < 4; nt++){
                float b2 = rb2s[nt*16 + l15];
                #pragma unroll
                for (int e = 0; e < 4; e++){
                    int row = w*48 + mt*16 + q*4 + e;
                    smH[row*72 + nt*16 + l15] = f2bf(sspf(hacc[mt*4+nt][e] + b2));
                }
            }
        // contraction: acc += R(own rows) @ B-tile
        #pragma unroll
        for (int kq = 0; kq < 2; kq++){
            bf16x8 af[3];
            #pragma unroll
            for (int mt = 0; mt < 3; mt++)
                af[mt] = *(const bf16x8*)(smH + (w*48 + mt*16 + l15)*72 + kq*32 + q*8);
            #pragma unroll
            for (int nt = 0; nt < 8; nt++){
                bf16x8 bb = *(const bf16x8*)(smB[buf] + (nt*16 + l15)*72 + kq*32 + q*8);
                #pragma unroll
                for (int mt = 0; mt < 3; mt++)
                    acc[mt*8+nt] = __builtin_amdgcn_mfma_f32_16x16x32_bf16(af[mt], bb, acc[mt*8+nt], 0, 0, 0);
            }
        }
    }
    // epilogue: LDS-staged contiguous write of part tile (192x128 bf16)
    unsigned short* stg = smH;               // row stride 136 shorts
    #pragma unroll
    for (int half = 0; half < 2; half++){
        __syncthreads();
        if ((w >> 1) == half){
            int wl = w & 1;
            #pragma unroll
            for (int mt = 0; mt < 3; mt++)
                #pragma unroll
                for (int nt = 0; nt < 8; nt++)
                    #pragma unroll
                    for (int e = 0; e < 4; e++){
                        int row = wl*48 + mt*16 + q*4 + e;      // [0,96)
                        stg[row*136 + nt*16 + l15] = f2bf(acc[mt*8+nt][e]);
                    }
        }
        __syncthreads();
        unsigned short* gdst = part + ((size_t)(z*NKC + kc)*NATOMS + half*96)*128;
        #pragma unroll
        for (int it = 0; it < 6; it++){
            int flat = tid + it*256;          // [0,1536) uint4s
            int row = flat >> 4, cc = flat & 15;
            uint4 v = *(const uint4*)(stg + row*136 + cc*8);
            *(uint4*)(gdst + row*128 + cc*8) = v;
        }
    }
}

// ---------------- reduce partials + sp + mask -> bf16 next features
__global__ void k_reduceB(const unsigned short* __restrict__ part, const float* __restrict__ mask,
                          unsigned short* __restrict__ fb, unsigned short* __restrict__ fc){
    int zl = blockIdx.y;
    int idx = blockIdx.x*256 + threadIdx.x;    // [0, 24576)
    int a = idx >> 7, j2 = idx & 127;
    const unsigned short* p = part + ((size_t)(zl*NKC)*NATOMS + a)*128 + j2;
    float s = 0.f;
    #pragma unroll
    for (int c = 0; c < NKC; c++) s += bf2f(p[(size_t)c*NATOMS*128]);
    int rowg = zl*NATOMS + a;
    float v = spf_act(s) * mask[rowg];
    if (j2 < 64) fb[rowg*64 + j2] = f2bf(v);
    else         fc[rowg*64 + j2 - 64] = f2bf(v);
}

// ---------------- fused head: h1 + BN1 + leaky + h2 + BN2 + leaky + mask -> y2
__global__ __launch_bounds__(256) void k_head(
    const unsigned short* __restrict__ fbio, const unsigned short* __restrict__ fch,
    const float* __restrict__ fW1, const float* __restrict__ fb1,
    const float* __restrict__ fW2, const float* __restrict__ fb2,
    const float* __restrict__ mask, float* __restrict__ y2)
{
    __shared__ float X[2048];
    __shared__ float red[16];
    __shared__ float stats[2];
    int a = blockIdx.x, tid = threadIdx.x;
    int lane = tid & 63, w = tid >> 6;

    #pragma unroll
    for (int i = 0; i < 8; i++){
        int idx = tid + i*256; int z = idx >> 7, c = idx & 127;
        int row = z*NATOMS + a;
        X[idx] = (c < 64) ? bf2f(fbio[row*64 + c]) : bf2f(fch[row*64 + c - 64]);
    }
    __syncthreads();
    f32x4 v[2]; float s = 0.f, ss = 0.f;
    #pragma unroll
    for (int i = 0; i < 2; i++){
        int idx4 = tid + i*256; int z = idx4 >> 5, k4 = (idx4 & 31)*4;
        f32x4 acc = { fb1[k4], fb1[k4+1], fb1[k4+2], fb1[k4+3] };
        #pragma unroll 4
        for (int c = 0; c < 128; c++){
            float xv = X[z*128 + c];
            float4 wv = *(const float4*)(fW1 + (size_t)c*128 + k4);
            acc[0] += xv*wv.x; acc[1] += xv*wv.y; acc[2] += xv*wv.z; acc[3] += xv*wv.w;
        }
        v[i] = acc;
        s += acc[0]+acc[1]+acc[2]+acc[3];
        ss += acc[0]*acc[0]+acc[1]*acc[1]+acc[2]*acc[2]+acc[3]*acc[3];
    }
    for (int off = 32; off; off >>= 1){ s += __shfl_down(s, off); ss += __shfl_down(ss, off); }
    if (!lane){ red[w] = s; red[8+w] = ss; }
    __syncthreads();
    if (!tid){
        float S = red[0]+red[1]+red[2]+red[3];
        float SS = red[8]+red[9]+red[10]+red[11];
        float m = S*(1.f/2048.f), var = SS*(1.f/2048.f) - m*m;
        stats[0] = m; stats[1] = rsqrtf(var + 1e-5f);
    }
    __syncthreads();
    float m1 = stats[0], inv1 = stats[1];
    #pragma unroll
    for (int i = 0; i < 2; i++){
        int idx4 = tid + i*256;
        f32x4 t;
        #pragma unroll
        for (int e = 0; e < 4; e++){
            float x = (v[i][e]-m1)*inv1;
            t[e] = (x > 0.f) ? x : 0.2f*x;
        }
        *(f32x4*)(X + idx4*4) = t;
    }
    __syncthreads();
    float u[2]; s = 0.f; ss = 0.f;
    #pragma unroll
    for (int i = 0; i < 2; i++){
        int idx = tid + i*256; int z = idx >> 5, j = idx & 31;
        float acc = fb2[j];
        #pragma unroll 8
        for (int k = 0; k < 128; k++) acc += X[z*128 + k]*fW2[k*32 + j];
        u[i] = acc; s += acc; ss += acc*acc;
    }
    for (int off = 32; off; off >>= 1){ s += __shfl_down(s, off); ss += __shfl_down(ss, off); }
    if (!lane){ red[w] = s; red[8+w] = ss; }
    __syncthreads();
    if (!tid){
        float S = red[0]+red[1]+red[2]+red[3];
        float SS = red[8]+red[9]+red[10]+red[11];
        float m = S*(1.f/512.f), var = SS*(1.f/512.f) - m*m;
        stats[0] = m; stats[1] = rsqrtf(var + 1e-5f);
    }
    __syncthreads();
    float m2 = stats[0], inv2 = stats[1];
    #pragma unroll
    for (int i = 0; i < 2; i++){
        int idx = tid + i*256; int z = idx >> 5, j = idx & 31;
        float x = (u[i]-m2)*inv2;
        x = (x > 0.f) ? x : 0.2f*x;
        y2[(size_t)(z*NATOMS + a)*32 + j] = x * mask[z*NATOMS + a];
    }
}

// ---------------- out[z,j] = sum_a y2[z,a,j]
__global__ void k_sum(const float* __restrict__ y2, float* __restrict__ out){
    int e = blockIdx.x;           // 512 outputs
    int z = e >> 5, jj = e & 31;
    int tid = threadIdx.x;        // 64
    float s = 0.f;
    for (int a = tid; a < NATOMS; a += 64) s += y2[(z*NATOMS + a)*32 + jj];
    for (int off = 32; off; off >>= 1) s += __shfl_down(s, off);
    if (!tid) out[e] = s;
}

extern "C" void kernel_launch(void* const* d_in, const int* in_sizes, int n_in,
                              void* d_out, int out_size, void* d_ws, size_t ws_size,
                              hipStream_t stream){
    const float* features = (const float*)d_in[0];
    const float* geometry = (const float*)d_in[1];
    const float* mask     = (const float*)d_in[2];
    const float* W_bio    = (const float*)d_in[3];
    const float* b_bio    = (const float*)d_in[4];
    const float* W_ch     = (const float*)d_in[5];
    const float* b_ch     = (const float*)d_in[6];
    const float* rW1[2] = {(const float*)d_in[7],  (const float*)d_in[12]};
    const float* rb1[2] = {(const float*)d_in[8],  (const float*)d_in[13]};
    const float* rW2[2] = {(const float*)d_in[9],  (const float*)d_in[14]};
    const float* rb2[2] = {(const float*)d_in[10], (const float*)d_in[15]};
    const float* rWo[2] = {(const float*)d_in[11], (const float*)d_in[16]};
    const float* fW1 = (const float*)d_in[17];
    const float* fb1 = (const float*)d_in[18];
    const float* fW2 = (const float*)d_in[19];
    const float* fb2 = (const float*)d_in[20];

    char* ws = (char*)d_ws;
    unsigned short* fAb = (unsigned short*)ws;   ws += (size_t)ZA*64*2;
    unsigned short* fAc = (unsigned short*)ws;   ws += (size_t)ZA*64*2;
    unsigned short* fBb = (unsigned short*)ws;   ws += (size_t)ZA*64*2;
    unsigned short* fBc = (unsigned short*)ws;   ws += (size_t)ZA*64*2;
    unsigned short* w2T = (unsigned short*)ws;   ws += (size_t)4096*2;
    unsigned short* Tg = (unsigned short*)ws;    ws += (size_t)ZA*8192*2;            // 50.3 MB
    unsigned short* part = (unsigned short*)ws;  ws += (size_t)ZB*NKC*NATOMS*128*2;   // 25.2 MB
    float* y2 = (float*)ws;                      ws += (size_t)ZA*32*4;

    dim3 gt(24, 32, 2);
    dim3 gf(ZB, NKC);
    dim3 gd(96, ZB);
    // layer 0 (encode fused into tmpB)
    k_prep2<<<16, 256, 0, stream>>>(rW2[0], w2T);
    k_tmpB<<<gt, 256, 0, stream>>>(nullptr, nullptr, features, W_bio, b_bio, W_ch, b_ch,
                                   mask, rWo[0], Tg);
    k_fused<<<gf, 256, 0, stream>>>(geometry, rW1[0], rb1[0], w2T, rb2[0], Tg, part);
    k_reduceB<<<gd, 256, 0, stream>>>(part, mask, fAb, fAc);
    // layer 1
    k_prep2<<<16, 256, 0, stream>>>(rW2[1], w2T);
    k_tmpB<<<gt, 256, 0, stream>>>(fAb, fAc, nullptr, W_bio, b_bio, W_ch, b_ch,
                                   mask, rWo[1], Tg);
    k_fused<<<gf, 256, 0, stream>>>(geometry, rW1[1], rb1[1], w2T, rb2[1], Tg, part);
    k_reduceB<<<gd, 256, 0, stream>>>(part, mask, fBb, fBc);
    // fused head + final sum
    k_head<<<NATOMS, 256, 0, stream>>>(fBb, fBc, fW1, fb1, fW2, fb2, mask, y2);
    k_sum<<<512, 64, 0, stream>>>(y2, (float*)d_out);
}

// Round 12
// 262.026 us; speedup vs baseline: 1.4528x; 1.0691x over previous
//
#include <hip/hip_runtime.h>
#include <math.h>

#define ZB 16
#define NATOMS 192
#define NBAS 40
#define ZA (ZB*NATOMS)       // 3072
#define NKC 32               // K-chunks in contraction

typedef __attribute__((ext_vector_type(4))) float f32x4;
typedef __attribute__((ext_vector_type(8))) short bf16x8;

__device__ __forceinline__ unsigned short f2bf(float x){
    union { float f; unsigned u; } v; v.f = x;
    unsigned r = v.u + 0x7FFFu + ((v.u >> 16) & 1u);
    return (unsigned short)(r >> 16);
}
// truncating bf16 (1 op) — for hot paths; bias ~0.2% rel, fine vs 7.64 threshold
__device__ __forceinline__ unsigned short f2bf_t(float x){
    union { float f; unsigned u; } v; v.f = x;
    return (unsigned short)(v.u >> 16);
}
__device__ __forceinline__ float bf2f(unsigned short u){
    union { unsigned u; float f; } v; v.u = ((unsigned)u) << 16; return v.f;
}
__device__ __forceinline__ float bits2f(unsigned u){
    union { unsigned u; float f; } v; v.u = u; return v.f;
}
__device__ __forceinline__ unsigned f2bits(float x){
    union { float f; unsigned u; } v; v.f = x; return v.u;
}
// full ssp with overflow guard (for potentially-large inputs)
__device__ __forceinline__ float sspf(float x){
    float t = 7.2134752f*x;
    float tc = fminf(t, 126.f);
    float e = __builtin_amdgcn_exp2f(tc);
    float l = __builtin_amdgcn_logf(1.f + e);   // log2
    float r = fmaf(l, 0.13862944f, -0.13862944f);
    return (t > 126.f) ? (x - 0.13862944f) : r;
}
// lean ssp: valid for x << 17 (h1/R pre-activations are |x| <~ 2)
__device__ __forceinline__ float sspf_lean(float x){
    float t = fminf(7.2134752f*x, 126.f);
    float e = __builtin_amdgcn_exp2f(t);
    float l = __builtin_amdgcn_logf(1.f + e);
    return fmaf(l, 0.13862944f, -0.13862944f);
}
__device__ __forceinline__ float spf_act(float x){
    float t = 7.2134752f*x;
    float tc = fminf(t, 126.f);
    float e = __builtin_amdgcn_exp2f(tc);
    float l = __builtin_amdgcn_logf(1.f + e);
    float r = l*0.13862944f;
    return (t > 126.f) ? x : r;
}

// ---------------- prep: w2T[layer][hout*64+hin] = bf16(rW2[hin][hout]), both layers
__global__ void k_prep2(const float* __restrict__ rW2_0, const float* __restrict__ rW2_1,
                        unsigned short* __restrict__ w2T){
    int idx = blockIdx.x*256 + threadIdx.x;     // [0,8192)
    int l = idx >> 12, r = idx & 4095;
    int hout = r >> 6, hin = r & 63;
    const float* src = l ? rW2_1 : rW2_0;
    w2T[idx] = f2bf(src[hin*64 + hout]);
}

// ---------------- tmp GEMM bf16 MFMA: Tg[m][s*4096 + j*64 + h] = (f_s[m] @ rWo[h][j][:]) * mask*c
// layer 0 (feat != null): f_s rows computed on the fly from the linear encoders.
__global__ __launch_bounds__(256,2) void k_tmpB(
    const unsigned short* __restrict__ fb, const unsigned short* __restrict__ fc,
    const float* __restrict__ feat,
    const float* __restrict__ Wb, const float* __restrict__ bb,
    const float* __restrict__ Wc, const float* __restrict__ bc,
    const float* __restrict__ mask, const float* __restrict__ rWo,
    unsigned short* __restrict__ Tg)
{
    __shared__ unsigned short sm[18432];   // As[128*72] | Bs[128*72]; Cs overlays all
    __shared__ float msk[128];
    __shared__ float featS[128*8];
    __shared__ float WbS[7*64];
    __shared__ float bbS[64], WcS[64], bcS[64];
    unsigned short* As = sm;
    unsigned short* Bs = sm + 9216;
    unsigned short* Cs = sm;

    int tid = threadIdx.x;
    int m0 = blockIdx.x*128, n0 = blockIdx.y*128, s = blockIdx.z;
    int lane = tid & 63, w = tid >> 6, q = lane >> 4, l15 = lane & 15;
    int wm = w & 1, wn = w >> 1;

    if (feat){
        #pragma unroll
        for (int it = 0; it < 4; it++){
            int idx = tid + it*256;            // 1024 floats
            featS[idx] = feat[(size_t)m0*8 + idx];
        }
        for (int i = tid; i < 448; i += 256) WbS[i] = Wb[i];   // 7x64, strided
        if (tid < 64){ bbS[tid] = bb[tid]; WcS[tid] = Wc[tid]; bcS[tid] = bc[tid]; }
        __syncthreads();
        #pragma unroll
        for (int it = 0; it < 32; it++){
            int idx = tid + it*256;            // 8192
            int r = idx >> 6, e = idx & 63;
            float acc;
            if (s == 0){
                acc = bbS[e];
                #pragma unroll
                for (int c = 0; c < 7; c++) acc += featS[r*8+c]*WbS[c*64+e];
            } else {
                acc = bcS[e] + featS[r*8+7]*WcS[e];
            }
            As[r*72 + e] = f2bf(acc);
        }
    } else {
        const unsigned short* f = s ? fc : fb;
        #pragma unroll
        for (int it = 0; it < 4; it++){
            int idx = tid + it*256;            // 1024 uint4
            int r = idx >> 3, c8 = idx & 7;
            *(uint4*)(As + r*72 + c8*8) = *(const uint4*)(f + (size_t)(m0 + r)*64 + c8*8);
        }
    }
    // B-staging: row r -> n = n0+r = j*64+h -> rWo[(h*64+j)*64 + i], fp32->bf16
    #pragma unroll
    for (int it = 0; it < 8; it++){
        int idx = tid + it*256;                // 2048 float4
        int r = idx >> 4, c4 = idx & 15;
        int n = n0 + r;
        int j = n >> 6, h = n & 63;
        float4 v = *(const float4*)(rWo + (size_t)(h*64 + j)*64 + c4*4);
        ushort4 o; o.x = f2bf(v.x); o.y = f2bf(v.y); o.z = f2bf(v.z); o.w = f2bf(v.w);
        *(ushort4*)(Bs + r*72 + c4*4) = o;
    }
    if (tid < 128) msk[tid] = mask[m0 + tid] * 0.07216878364870322f;
    __syncthreads();

    f32x4 acc[16];
    #pragma unroll
    for (int i = 0; i < 16; i++) acc[i] = (f32x4){0.f,0.f,0.f,0.f};
    #pragma unroll
    for (int kc = 0; kc < 2; kc++){
        bf16x8 af[4];
        #pragma unroll
        for (int mt = 0; mt < 4; mt++)
            af[mt] = *(const bf16x8*)(As + (wm*64 + mt*16 + l15)*72 + kc*32 + q*8);
        #pragma unroll
        for (int nt = 0; nt < 4; nt++){
            bf16x8 bf_ = *(const bf16x8*)(Bs + (wn*64 + nt*16 + l15)*72 + kc*32 + q*8);
            #pragma unroll
            for (int mt = 0; mt < 4; mt++)
                acc[mt*4+nt] = __builtin_amdgcn_mfma_f32_16x16x32_bf16(af[mt], bf_, acc[mt*4+nt], 0, 0, 0);
        }
    }
    __syncthreads();   // all As/Bs reads done -> overlay Cs
    #pragma unroll
    for (int mt = 0; mt < 4; mt++)
        #pragma unroll
        for (int nt = 0; nt < 4; nt++)
            #pragma unroll
            for (int e = 0; e < 4; e++){
                int row2 = mt*16 + q*4 + e;
                float v = acc[mt*4+nt][e] * msk[wm*64 + row2];
                Cs[w*4608 + row2*72 + nt*16 + l15] = f2bf(v);
            }
    __syncthreads();
    #pragma unroll
    for (int it = 0; it < 8; it++){
        int flat = lane + it*64;               // [0,512)
        int rr = flat >> 3, c8 = flat & 7;
        uint4 v = *(const uint4*)(Cs + w*4608 + rr*72 + c8*8);
        size_t dst = (size_t)(m0 + wm*64 + rr)*8192 + s*4096 + n0 + wn*64 + c8*8;
        *(uint4*)(Tg + dst) = v;
    }
}

// ---------------- FUSED radial + contraction. Grid (ZB, NKC).
// h1 built directly into MFMA A-fragment registers; lean ssp + truncating packs.
__global__ __launch_bounds__(256,2) void k_fused(
    const float* __restrict__ geom,
    const float* __restrict__ rW1, const float* __restrict__ rb1,
    const unsigned short* __restrict__ w2T, const float* __restrict__ rb2,
    const unsigned short* __restrict__ Tc,
    unsigned short* __restrict__ part)
{
    __shared__ unsigned short smH[192*72];      // 27648 B: R tile -> epilogue staging
    __shared__ unsigned short smB[2][128*72];   // 36864 B: Tg tile double buffer
    __shared__ unsigned short W1bf[NBAS*72];    // 5760 B, rows padded to 72
    __shared__ float rb2s[64];

    int tid = threadIdx.x;
    int z = blockIdx.x, kc = blockIdx.y;
    int lane = tid & 63, w = tid >> 6, q = lane >> 4, l15 = lane & 15;
    int a_r = tid >> 3, c8 = tid & 7;

    // stage W1 as bf16 (rows padded 72)
    #pragma unroll
    for (int i = 0; i < 10; i++){
        int idx = tid + i*256;                 // [0,2560)
        int r = idx >> 6, c = idx & 63;
        W1bf[r*72 + c] = f2bf(rW1[idx]);
    }
    if (tid < 64) rb2s[tid] = rb2[tid];

    // rW2^T fragments in registers (verified layout)
    bf16x8 bfr[2][4];
    #pragma unroll
    for (int kq = 0; kq < 2; kq++)
        #pragma unroll
        for (int nt = 0; nt < 4; nt++)
            bfr[kq][nt] = *(const bf16x8*)(w2T + (nt*16 + l15)*64 + kq*32 + q*8);

    // rb1 bias slice for this lane's k-positions: rb1[kq*32 + q*8 + j]
    float rb1v[2][8];
    #pragma unroll
    for (int kq = 0; kq < 2; kq++){
        float4 t0 = *(const float4*)(rb1 + kq*32 + q*8);
        float4 t1 = *(const float4*)(rb1 + kq*32 + q*8 + 4);
        rb1v[kq][0]=t0.x; rb1v[kq][1]=t0.y; rb1v[kq][2]=t0.z; rb1v[kq][3]=t0.w;
        rb1v[kq][4]=t1.x; rb1v[kq][5]=t1.y; rb1v[kq][6]=t1.z; rb1v[kq][7]=t1.w;
    }

    // this lane's 3 a-rows' geometry (rows w*48 + mt*16 + l15)
    float gaxr[3], gayr[3], gazr[3];
    #pragma unroll
    for (int mt = 0; mt < 3; mt++){
        int ar = w*48 + mt*16 + l15;
        const float* gp = geom + (size_t)(z*NATOMS + ar)*3;
        gaxr[mt] = gp[0]; gayr[mt] = gp[1]; gazr[mt] = gp[2];
    }

    const size_t Tbase = (size_t)z*NATOMS*8192;
    uint4 rbv[4];
    {
        const unsigned short* Bb = Tc + Tbase + (size_t)(kc*6)*8192;
        #pragma unroll
        for (int r = 0; r < 4; r++) rbv[r] = *(const uint4*)(Bb + (size_t)(a_r + 32*r)*64 + c8*8);
    }

    f32x4 acc[24];
    #pragma unroll
    for (int i = 0; i < 24; i++) acc[i] = (f32x4){0.f,0.f,0.f,0.f};

    __syncthreads();           // W1bf / rb2s staged

    for (int i = 0; i < 6; i++){
        int buf = i & 1;
        int b = kc*6 + i;
        // commit prefetched B tile to LDS (buf last read 2 iters ago; barrier(i-1) covers)
        #pragma unroll
        for (int r = 0; r < 4; r++) *(uint4*)(smB[buf] + (a_r + 32*r)*72 + c8*8) = rbv[r];
        // prefetch next b
        if (i < 5){
            const unsigned short* Bb = Tc + Tbase + (size_t)(b+1)*8192;
            #pragma unroll
            for (int r = 0; r < 4; r++) rbv[r] = *(const uint4*)(Bb + (size_t)(a_r + 32*r)*64 + c8*8);
        }
        // pair coefficients for this lane's 3 rows (registers, no LDS)
        const float* gb = geom + (size_t)(z*NATOMS + b)*3;
        float gbx = gb[0], gby = gb[1], gbz = gb[2];
        float c0r[3], c1r[3]; int o0r[3], o1r[3];
        #pragma unroll
        for (int mt = 0; mt < 3; mt++){
            float dx = gaxr[mt]-gbx, dy = gayr[mt]-gby, dz = gazr[mt]-gbz;
            float r = sqrtf(dx*dx + dy*dy + dz*dz);
            float u = r * 3.9f;
            int k0 = (int)u;
            float fr = u - (float)k0;
            float cs = __cosf(fr * 1.57079632679489662f);
            float c0 = cs*cs, c1 = 1.f - c0;
            if (k0   >= NBAS) c0 = 0.f;
            if (k0+1 >= NBAS) c1 = 0.f;
            c0r[mt] = c0; c1r[mt] = c1;
            o0r[mt] = min(k0, NBAS-1)*72;
            o1r[mt] = min(k0+1, NBAS-1)*72;
        }
        __syncthreads();       // smB[buf] visible to all waves
        // h2: R_pre = h1 @ rW2, with h1 A-frags built in registers
        f32x4 hacc[12];
        #pragma unroll
        for (int t = 0; t < 12; t++) hacc[t] = (f32x4){0.f,0.f,0.f,0.f};
        #pragma unroll
        for (int kq = 0; kq < 2; kq++){
            #pragma unroll
            for (int mt = 0; mt < 3; mt++){
                uint4 w0 = *(const uint4*)(W1bf + o0r[mt] + kq*32 + q*8);
                uint4 w1 = *(const uint4*)(W1bf + o1r[mt] + kq*32 + q*8);
                const unsigned* w0p = (const unsigned*)&w0;
                const unsigned* w1p = (const unsigned*)&w1;
                uint4 af_u;
                unsigned* ap = (unsigned*)&af_u;
                #pragma unroll
                for (int d = 0; d < 4; d++){
                    float a0 = bits2f(w0p[d] << 16);
                    float a1 = bits2f(w0p[d] & 0xffff0000u);
                    float b0 = bits2f(w1p[d] << 16);
                    float b1 = bits2f(w1p[d] & 0xffff0000u);
                    float v0 = fmaf(c1r[mt], b0, fmaf(c0r[mt], a0, rb1v[kq][2*d]));
                    float v1 = fmaf(c1r[mt], b1, fmaf(c0r[mt], a1, rb1v[kq][2*d+1]));
                    unsigned u0 = f2bits(sspf_lean(v0));
                    unsigned u1 = f2bits(sspf_lean(v1));
                    ap[d] = (u0 >> 16) | (u1 & 0xffff0000u);
                }
                bf16x8 af = *(bf16x8*)&af_u;
                #pragma unroll
                for (int nt = 0; nt < 4; nt++)
                    hacc[mt*4+nt] = __builtin_amdgcn_mfma_f32_16x16x32_bf16(af, bfr[kq][nt], hacc[mt*4+nt], 0, 0, 0);
            }
        }
        // R = ssp(R_pre + rb2) -> smH (own rows; wave-local in-order)
        #pragma unroll
        for (int mt = 0; mt < 3; mt++)
            #pragma unroll
            for (int nt = 0; nt < 4; nt++){
                float b2 = rb2s[nt*16 + l15];
                #pragma unroll
                for (int e = 0; e < 4; e++){
                    int row = w*48 + mt*16 + q*4 + e;
                    smH[row*72 + nt*16 + l15] = f2bf_t(sspf_lean(hacc[mt*4+nt][e] + b2));
                }
            }
        // contraction: acc += R(own rows) @ B-tile
        #pragma unroll
        for (int kq = 0; kq < 2; kq++){
            bf16x8 af[3];
            #pragma unroll
            for (int mt = 0; mt < 3; mt++)
                af[mt] = *(const bf16x8*)(smH + (w*48 + mt*16 + l15)*72 + kq*32 + q*8);
            #pragma unroll
            for (int nt = 0; nt < 8; nt++){
                bf16x8 bb = *(const bf16x8*)(smB[buf] + (nt*16 + l15)*72 + kq*32 + q*8);
                #pragma unroll
                for (int mt = 0; mt < 3; mt++)
                    acc[mt*8+nt] = __builtin_amdgcn_mfma_f32_16x16x32_bf16(af[mt], bb, acc[mt*8+nt], 0, 0, 0);
            }
        }
    }
    // epilogue: LDS-staged contiguous write of part tile (192x128 bf16)
    unsigned short* stg = smH;               // row stride 136 shorts
    #pragma unroll
    for (int half = 0; half < 2; half++){
        __syncthreads();
        if ((w >> 1) == half){
            int wl = w & 1;
            #pragma unroll
            for (int mt = 0; mt < 3; mt++)
                #pragma unroll
                for (int nt = 0; nt < 8; nt++)
                    #pragma unroll
                    for (int e = 0; e < 4; e++){
                        int row = wl*48 + mt*16 + q*4 + e;      // [0,96)
                        stg[row*136 + nt*16 + l15] = f2bf_t(acc[mt*8+nt][e]);
                    }
        }
        __syncthreads();
        unsigned short* gdst = part + ((size_t)(z*NKC + kc)*NATOMS + half*96)*128;
        #pragma unroll
        for (int it = 0; it < 6; it++){
            int flat = tid + it*256;          // [0,1536) uint4s
            int row = flat >> 4, cc = flat & 15;
            uint4 v = *(const uint4*)(stg + row*136 + cc*8);
            *(uint4*)(gdst + row*128 + cc*8) = v;
        }
    }
}

// ---------------- reduce partials + sp + mask -> bf16 next features
__global__ void k_reduceB(const unsigned short* __restrict__ part, const float* __restrict__ mask,
                          unsigned short* __restrict__ fb, unsigned short* __restrict__ fc){
    int zl = blockIdx.y;
    int idx = blockIdx.x*256 + threadIdx.x;    // [0, 24576)
    int a = idx >> 7, j2 = idx & 127;
    const unsigned short* p = part + ((size_t)(zl*NKC)*NATOMS + a)*128 + j2;
    float s = 0.f;
    #pragma unroll
    for (int c = 0; c < NKC; c++) s += bf2f(p[(size_t)c*NATOMS*128]);
    int rowg = zl*NATOMS + a;
    float v = spf_act(s) * mask[rowg];
    if (j2 < 64) fb[rowg*64 + j2] = f2bf(v);
    else         fc[rowg*64 + j2 - 64] = f2bf(v);
}

// ---------------- fused head: h1 + BN1 + leaky + h2 + BN2 + leaky + mask -> y2
__global__ __launch_bounds__(256) void k_head(
    const unsigned short* __restrict__ fbio, const unsigned short* __restrict__ fch,
    const float* __restrict__ fW1, const float* __restrict__ fb1,
    const float* __restrict__ fW2, const float* __restrict__ fb2,
    const float* __restrict__ mask, float* __restrict__ y2)
{
    __shared__ float X[2048];
    __shared__ float red[16];
    __shared__ float stats[2];
    int a = blockIdx.x, tid = threadIdx.x;
    int lane = tid & 63, w = tid >> 6;

    #pragma unroll
    for (int i = 0; i < 8; i++){
        int idx = tid + i*256; int z = idx >> 7, c = idx & 127;
        int row = z*NATOMS + a;
        X[idx] = (c < 64) ? bf2f(fbio[row*64 + c]) : bf2f(fch[row*64 + c - 64]);
    }
    __syncthreads();
    f32x4 v[2]; float s = 0.f, ss = 0.f;
    #pragma unroll
    for (int i = 0; i < 2; i++){
        int idx4 = tid + i*256; int z = idx4 >> 5, k4 = (idx4 & 31)*4;
        f32x4 acc = { fb1[k4], fb1[k4+1], fb1[k4+2], fb1[k4+3] };
        #pragma unroll 4
        for (int c = 0; c < 128; c++){
            float xv = X[z*128 + c];
            float4 wv = *(const float4*)(fW1 + (size_t)c*128 + k4);
            acc[0] += xv*wv.x; acc[1] += xv*wv.y; acc[2] += xv*wv.z; acc[3] += xv*wv.w;
        }
        v[i] = acc;
        s += acc[0]+acc[1]+acc[2]+acc[3];
        ss += acc[0]*acc[0]+acc[1]*acc[1]+acc[2]*acc[2]+acc[3]*acc[3];
    }
    for (int off = 32; off; off >>= 1){ s += __shfl_down(s, off); ss += __shfl_down(ss, off); }
    if (!lane){ red[w] = s; red[8+w] = ss; }
    __syncthreads();
    if (!tid){
        float S = red[0]+red[1]+red[2]+red[3];
        float SS = red[8]+red[9]+red[10]+red[11];
        float m = S*(1.f/2048.f), var = SS*(1.f/2048.f) - m*m;
        stats[0] = m; stats[1] = rsqrtf(var + 1e-5f);
    }
    __syncthreads();
    float m1 = stats[0], inv1 = stats[1];
    #pragma unroll
    for (int i = 0; i < 2; i++){
        int idx4 = tid + i*256;
        f32x4 t;
        #pragma unroll
        for (int e = 0; e < 4; e++){
            float x = (v[i][e]-m1)*inv1;
            t[e] = (x > 0.f) ? x : 0.2f*x;
        }
        *(f32x4*)(X + idx4*4) = t;
    }
    __syncthreads();
    float u[2]; s = 0.f; ss = 0.f;
    #pragma unroll
    for (int i = 0; i < 2; i++){
        int idx = tid + i*256; int z = idx >> 5, j = idx & 31;
        float acc = fb2[j];
        #pragma unroll 8
        for (int k = 0; k < 128; k++) acc += X[z*128 + k]*fW2[k*32 + j];
        u[i] = acc; s += acc; ss += acc*acc;
    }
    for (int off = 32; off; off >>= 1){ s += __shfl_down(s, off); ss += __shfl_down(ss, off); }
    if (!lane){ red[w] = s; red[8+w] = ss; }
    __syncthreads();
    if (!tid){
        float S = red[0]+red[1]+red[2]+red[3];
        float SS = red[8]+red[9]+red[10]+red[11];
        float m = S*(1.f/512.f), var = SS*(1.f/512.f) - m*m;
        stats[0] = m; stats[1] = rsqrtf(var + 1e-5f);
    }
    __syncthreads();
    float m2 = stats[0], inv2 = stats[1];
    #pragma unroll
    for (int i = 0; i < 2; i++){
        int idx = tid + i*256; int z = idx >> 5, j = idx & 31;
        float x = (u[i]-m2)*inv2;
        x = (x > 0.f) ? x : 0.2f*x;
        y2[(size_t)(z*NATOMS + a)*32 + j] = x * mask[z*NATOMS + a];
    }
}

// ---------------- out[z,j] = sum_a y2[z,a,j]
__global__ void k_sum(const float* __restrict__ y2, float* __restrict__ out){
    int e = blockIdx.x;           // 512 outputs
    int z = e >> 5, jj = e & 31;
    int tid = threadIdx.x;        // 64
    float s = 0.f;
    for (int a = tid; a < NATOMS; a += 64) s += y2[(z*NATOMS + a)*32 + jj];
    for (int off = 32; off; off >>= 1) s += __shfl_down(s, off);
    if (!tid) out[e] = s;
}

extern "C" void kernel_launch(void* const* d_in, const int* in_sizes, int n_in,
                              void* d_out, int out_size, void* d_ws, size_t ws_size,
                              hipStream_t stream){
    const float* features = (const float*)d_in[0];
    const float* geometry = (const float*)d_in[1];
    const float* mask     = (const float*)d_in[2];
    const float* W_bio    = (const float*)d_in[3];
    const float* b_bio    = (const float*)d_in[4];
    const float* W_ch     = (const float*)d_in[5];
    const float* b_ch     = (const float*)d_in[6];
    const float* rW1[2] = {(const float*)d_in[7],  (const float*)d_in[12]};
    const float* rb1[2] = {(const float*)d_in[8],  (const float*)d_in[13]};
    const float* rW2[2] = {(const float*)d_in[9],  (const float*)d_in[14]};
    const float* rb2[2] = {(const float*)d_in[10], (const float*)d_in[15]};
    const float* rWo[2] = {(const float*)d_in[11], (const float*)d_in[16]};
    const float* fW1 = (const float*)d_in[17];
    const float* fb1 = (const float*)d_in[18];
    const float* fW2 = (const float*)d_in[19];
    const float* fb2 = (const float*)d_in[20];

    char* ws = (char*)d_ws;
    unsigned short* fAb = (unsigned short*)ws;   ws += (size_t)ZA*64*2;
    unsigned short* fAc = (unsigned short*)ws;   ws += (size_t)ZA*64*2;
    unsigned short* fBb = (unsigned short*)ws;   ws += (size_t)ZA*64*2;
    unsigned short* fBc = (unsigned short*)ws;   ws += (size_t)ZA*64*2;
    unsigned short* w2T = (unsigned short*)ws;   ws += (size_t)2*4096*2;
    unsigned short* Tg = (unsigned short*)ws;    ws += (size_t)ZA*8192*2;            // 50.3 MB
    unsigned short* part = (unsigned short*)ws;  ws += (size_t)ZB*NKC*NATOMS*128*2;   // 25.2 MB
    float* y2 = (float*)ws;                      ws += (size_t)ZA*32*4;

    dim3 gt(24, 32, 2);
    dim3 gf(ZB, NKC);
    dim3 gd(96, ZB);
    // both layers' rW2 transposes in one launch
    k_prep2<<<32, 256, 0, stream>>>(rW2[0], rW2[1], w2T);
    // layer 0 (encode fused into tmpB)
    k_tmpB<<<gt, 256, 0, stream>>>(nullptr, nullptr, features, W_bio, b_bio, W_ch, b_ch,
                                   mask, rWo[0], Tg);
    k_fused<<<gf, 256, 0, stream>>>(geometry, rW1[0], rb1[0], w2T, rb2[0], Tg, part);
    k_reduceB<<<gd, 256, 0, stream>>>(part, mask, fAb, fAc);
    // layer 1
    k_tmpB<<<gt, 256, 0, stream>>>(fAb, fAc, nullptr, W_bio, b_bio, W_ch, b_ch,
                                   mask, rWo[1], Tg);
    k_fused<<<gf, 256, 0, stream>>>(geometry, rW1[1], rb1[1], w2T + 4096, rb2[1], Tg, part);
    k_reduceB<<<gd, 256, 0, stream>>>(part, mask, fBb, fBc);
    // fused head + final sum
    k_head<<<NATOMS, 256, 0, stream>>>(fBb, fBc, fW1, fb1, fW2, fb2, mask, y2);
    k_sum<<<512, 64, 0, stream>>>(y2, (float*)d_out);
}

// Round 13
// 254.706 us; speedup vs baseline: 1.4946x; 1.0287x over previous
//
#include <hip/hip_runtime.h>
#include <math.h>

#define ZB 16
#define NATOMS 192
#define NBAS 40
#define ZA (ZB*NATOMS)       // 3072
#define NKC 32               // K-chunks in contraction

typedef __attribute__((ext_vector_type(4))) float f32x4;
typedef __attribute__((ext_vector_type(8))) short bf16x8;

__device__ __forceinline__ unsigned short f2bf(float x){
    union { float f; unsigned u; } v; v.f = x;
    unsigned r = v.u + 0x7FFFu + ((v.u >> 16) & 1u);
    return (unsigned short)(r >> 16);
}
// truncating bf16 (1 op) — hot paths
__device__ __forceinline__ unsigned short f2bf_t(float x){
    union { float f; unsigned u; } v; v.f = x;
    return (unsigned short)(v.u >> 16);
}
__device__ __forceinline__ float bf2f(unsigned short u){
    union { unsigned u; float f; } v; v.u = ((unsigned)u) << 16; return v.f;
}
__device__ __forceinline__ float bits2f(unsigned u){
    union { unsigned u; float f; } v; v.u = u; return v.f;
}
__device__ __forceinline__ unsigned f2bits(float x){
    union { float f; unsigned u; } v; v.f = x; return v.u;
}
// lean ssp: inputs bounded (|x| << 17) so no overflow guard needed
__device__ __forceinline__ float sspf_lean(float x){
    float e = __builtin_amdgcn_exp2f(7.2134752f*x);
    float l = __builtin_amdgcn_logf(1.f + e);
    return fmaf(l, 0.13862944f, -0.13862944f);
}
__device__ __forceinline__ float spf_act(float x){
    float t = 7.2134752f*x;
    float tc = fminf(t, 126.f);
    float e = __builtin_amdgcn_exp2f(tc);
    float l = __builtin_amdgcn_logf(1.f + e);
    float r = l*0.13862944f;
    return (t > 126.f) ? x : r;
}

// ---------------- prep: w2T[layer][hout*64+hin] = bf16(rW2[hin][hout]) and
// Bp[layer][(j*64+h)*64 + i] = bf16(rWo[h][j][i]) — both layers, one launch
__global__ void k_prep(const float* __restrict__ rW2_0, const float* __restrict__ rW2_1,
                       const float* __restrict__ rWo_0, const float* __restrict__ rWo_1,
                       unsigned short* __restrict__ w2T, unsigned short* __restrict__ Bp){
    int idx = blockIdx.x*256 + threadIdx.x;
    if (idx < 8192){
        int l = idx >> 12, r = idx & 4095;
        int hout = r >> 6, hin = r & 63;
        const float* src = l ? rW2_1 : rW2_0;
        w2T[idx] = f2bf(src[hin*64 + hout]);
    }
    for (int i = idx; i < 2*262144; i += gridDim.x*256){
        int l = i >> 18, r = i & 262143;
        int n = r >> 6, ii = r & 63;       // n = j*64+h
        int j = n >> 6, h = n & 63;
        const float* src = l ? rWo_1 : rWo_0;
        Bp[i] = f2bf(src[(h*64 + j)*64 + ii]);
    }
}

// ---------------- tmp GEMM bf16 MFMA: Tg[m][s*4096 + j*64 + h] = (f_s[m] @ rWo[h][j][:]) * mask*c
// layer 0 (feat != null): f_s rows computed on the fly from the linear encoders.
__global__ __launch_bounds__(256,2) void k_tmpB(
    const unsigned short* __restrict__ fb, const unsigned short* __restrict__ fc,
    const float* __restrict__ feat,
    const float* __restrict__ Wb, const float* __restrict__ bb,
    const float* __restrict__ Wc, const float* __restrict__ bc,
    const float* __restrict__ mask, const unsigned short* __restrict__ Bp,
    unsigned short* __restrict__ Tg)
{
    __shared__ unsigned short sm[18432];   // As[128*72] | Bs[128*72]; Cs overlays all
    __shared__ float msk[128];
    __shared__ float featS[128*8];
    __shared__ float WbS[7*64];
    __shared__ float bbS[64], WcS[64], bcS[64];
    unsigned short* As = sm;
    unsigned short* Bs = sm + 9216;
    unsigned short* Cs = sm;

    int tid = threadIdx.x;
    int m0 = blockIdx.x*128, n0 = blockIdx.y*128, s = blockIdx.z;
    int lane = tid & 63, w = tid >> 6, q = lane >> 4, l15 = lane & 15;
    int wm = w & 1, wn = w >> 1;

    if (feat){
        #pragma unroll
        for (int it = 0; it < 4; it++){
            int idx = tid + it*256;            // 1024 floats
            featS[idx] = feat[(size_t)m0*8 + idx];
        }
        for (int i = tid; i < 448; i += 256) WbS[i] = Wb[i];   // 7x64, strided
        if (tid < 64){ bbS[tid] = bb[tid]; WcS[tid] = Wc[tid]; bcS[tid] = bc[tid]; }
        __syncthreads();
        #pragma unroll
        for (int it = 0; it < 32; it++){
            int idx = tid + it*256;            // 8192
            int r = idx >> 6, e = idx & 63;
            float acc;
            if (s == 0){
                acc = bbS[e];
                #pragma unroll
                for (int c = 0; c < 7; c++) acc += featS[r*8+c]*WbS[c*64+e];
            } else {
                acc = bcS[e] + featS[r*8+7]*WcS[e];
            }
            As[r*72 + e] = f2bf(acc);
        }
    } else {
        const unsigned short* f = s ? fc : fb;
        #pragma unroll
        for (int it = 0; it < 4; it++){
            int idx = tid + it*256;            // 1024 uint4
            int r = idx >> 3, c8 = idx & 7;
            *(uint4*)(As + r*72 + c8*8) = *(const uint4*)(f + (size_t)(m0 + r)*64 + c8*8);
        }
    }
    // B-staging: pure uint4 copies from pre-converted Bp rows
    #pragma unroll
    for (int it = 0; it < 4; it++){
        int idx = tid + it*256;                // 1024 uint4
        int r = idx >> 3, c8 = idx & 7;
        *(uint4*)(Bs + r*72 + c8*8) = *(const uint4*)(Bp + (size_t)(n0 + r)*64 + c8*8);
    }
    if (tid < 128) msk[tid] = mask[m0 + tid] * 0.07216878364870322f;
    __syncthreads();

    f32x4 acc[16];
    #pragma unroll
    for (int i = 0; i < 16; i++) acc[i] = (f32x4){0.f,0.f,0.f,0.f};
    #pragma unroll
    for (int kc = 0; kc < 2; kc++){
        bf16x8 af[4];
        #pragma unroll
        for (int mt = 0; mt < 4; mt++)
            af[mt] = *(const bf16x8*)(As + (wm*64 + mt*16 + l15)*72 + kc*32 + q*8);
        #pragma unroll
        for (int nt = 0; nt < 4; nt++){
            bf16x8 bf_ = *(const bf16x8*)(Bs + (wn*64 + nt*16 + l15)*72 + kc*32 + q*8);
            #pragma unroll
            for (int mt = 0; mt < 4; mt++)
                acc[mt*4+nt] = __builtin_amdgcn_mfma_f32_16x16x32_bf16(af[mt], bf_, acc[mt*4+nt], 0, 0, 0);
        }
    }
    __syncthreads();   // all As/Bs reads done -> overlay Cs
    #pragma unroll
    for (int mt = 0; mt < 4; mt++)
        #pragma unroll
        for (int nt = 0; nt < 4; nt++)
            #pragma unroll
            for (int e = 0; e < 4; e++){
                int row2 = mt*16 + q*4 + e;
                float v = acc[mt*4+nt][e] * msk[wm*64 + row2];
                Cs[w*4608 + row2*72 + nt*16 + l15] = f2bf_t(v);
            }
    __syncthreads();
    #pragma unroll
    for (int it = 0; it < 8; it++){
        int flat = lane + it*64;               // [0,512)
        int rr = flat >> 3, c8 = flat & 7;
        uint4 v = *(const uint4*)(Cs + w*4608 + rr*72 + c8*8);
        size_t dst = (size_t)(m0 + wm*64 + rr)*8192 + s*4096 + n0 + wn*64 + c8*8;
        *(uint4*)(Tg + dst) = v;
    }
}

// ---------------- FUSED radial + contraction. Grid (ZB, NKC).
__global__ __launch_bounds__(256,2) void k_fused(
    const float* __restrict__ geom,
    const float* __restrict__ rW1, const float* __restrict__ rb1,
    const unsigned short* __restrict__ w2T, const float* __restrict__ rb2,
    const unsigned short* __restrict__ Tc,
    unsigned short* __restrict__ part)
{
    __shared__ unsigned short smH[192*72];      // 27648 B: R tile -> epilogue staging
    __shared__ unsigned short smB[2][128*72];   // 36864 B: Tg tile double buffer
    __shared__ unsigned short W1bf[NBAS*72];    // 5760 B, rows padded to 72
    __shared__ float rb2s[64];

    int tid = threadIdx.x;
    int z = blockIdx.x, kc = blockIdx.y;
    int lane = tid & 63, w = tid >> 6, q = lane >> 4, l15 = lane & 15;
    int a_r = tid >> 3, c8 = tid & 7;

    #pragma unroll
    for (int i = 0; i < 10; i++){
        int idx = tid + i*256;                 // [0,2560)
        int r = idx >> 6, c = idx & 63;
        W1bf[r*72 + c] = f2bf(rW1[idx]);
    }
    if (tid < 64) rb2s[tid] = rb2[tid];

    bf16x8 bfr[2][4];
    #pragma unroll
    for (int kq = 0; kq < 2; kq++)
        #pragma unroll
        for (int nt = 0; nt < 4; nt++)
            bfr[kq][nt] = *(const bf16x8*)(w2T + (nt*16 + l15)*64 + kq*32 + q*8);

    float rb1v[2][8];
    #pragma unroll
    for (int kq = 0; kq < 2; kq++){
        float4 t0 = *(const float4*)(rb1 + kq*32 + q*8);
        float4 t1 = *(const float4*)(rb1 + kq*32 + q*8 + 4);
        rb1v[kq][0]=t0.x; rb1v[kq][1]=t0.y; rb1v[kq][2]=t0.z; rb1v[kq][3]=t0.w;
        rb1v[kq][4]=t1.x; rb1v[kq][5]=t1.y; rb1v[kq][6]=t1.z; rb1v[kq][7]=t1.w;
    }

    float gaxr[3], gayr[3], gazr[3];
    #pragma unroll
    for (int mt = 0; mt < 3; mt++){
        int ar = w*48 + mt*16 + l15;
        const float* gp = geom + (size_t)(z*NATOMS + ar)*3;
        gaxr[mt] = gp[0]; gayr[mt] = gp[1]; gazr[mt] = gp[2];
    }

    const size_t Tbase = (size_t)z*NATOMS*8192;
    uint4 rbv[4];
    {
        const unsigned short* Bb = Tc + Tbase + (size_t)(kc*6)*8192;
        #pragma unroll
        for (int r = 0; r < 4; r++) rbv[r] = *(const uint4*)(Bb + (size_t)(a_r + 32*r)*64 + c8*8);
    }

    f32x4 acc[24];
    #pragma unroll
    for (int i = 0; i < 24; i++) acc[i] = (f32x4){0.f,0.f,0.f,0.f};

    __syncthreads();           // W1bf / rb2s staged

    for (int i = 0; i < 6; i++){
        int buf = i & 1;
        int b = kc*6 + i;
        #pragma unroll
        for (int r = 0; r < 4; r++) *(uint4*)(smB[buf] + (a_r + 32*r)*72 + c8*8) = rbv[r];
        if (i < 5){
            const unsigned short* Bb = Tc + Tbase + (size_t)(b+1)*8192;
            #pragma unroll
            for (int r = 0; r < 4; r++) rbv[r] = *(const uint4*)(Bb + (size_t)(a_r + 32*r)*64 + c8*8);
        }
        const float* gb = geom + (size_t)(z*NATOMS + b)*3;
        float gbx = gb[0], gby = gb[1], gbz = gb[2];
        float c0r[3], c1r[3]; int o0r[3], o1r[3];
        #pragma unroll
        for (int mt = 0; mt < 3; mt++){
            float dx = gaxr[mt]-gbx, dy = gayr[mt]-gby, dz = gazr[mt]-gbz;
            float r = sqrtf(dx*dx + dy*dy + dz*dz);
            float u = r * 3.9f;
            int k0 = (int)u;
            float fr = u - (float)k0;
            float cs = __cosf(fr * 1.57079632679489662f);
            float c0 = cs*cs, c1 = 1.f - c0;
            if (k0   >= NBAS) c0 = 0.f;
            if (k0+1 >= NBAS) c1 = 0.f;
            c0r[mt] = c0; c1r[mt] = c1;
            o0r[mt] = min(k0, NBAS-1)*72;
            o1r[mt] = min(k0+1, NBAS-1)*72;
        }
        __syncthreads();       // smB[buf] visible to all waves
        f32x4 hacc[12];
        #pragma unroll
        for (int t = 0; t < 12; t++) hacc[t] = (f32x4){0.f,0.f,0.f,0.f};
        #pragma unroll
        for (int kq = 0; kq < 2; kq++){
            #pragma unroll
            for (int mt = 0; mt < 3; mt++){
                uint4 w0 = *(const uint4*)(W1bf + o0r[mt] + kq*32 + q*8);
                uint4 w1 = *(const uint4*)(W1bf + o1r[mt] + kq*32 + q*8);
                const unsigned* w0p = (const unsigned*)&w0;
                const unsigned* w1p = (const unsigned*)&w1;
                uint4 af_u;
                unsigned* ap = (unsigned*)&af_u;
                #pragma unroll
                for (int d = 0; d < 4; d++){
                    float a0 = bits2f(w0p[d] << 16);
                    float a1 = bits2f(w0p[d] & 0xffff0000u);
                    float b0 = bits2f(w1p[d] << 16);
                    float b1 = bits2f(w1p[d] & 0xffff0000u);
                    float v0 = fmaf(c1r[mt], b0, fmaf(c0r[mt], a0, rb1v[kq][2*d]));
                    float v1 = fmaf(c1r[mt], b1, fmaf(c0r[mt], a1, rb1v[kq][2*d+1]));
                    unsigned u0 = f2bits(sspf_lean(v0));
                    unsigned u1 = f2bits(sspf_lean(v1));
                    ap[d] = (u0 >> 16) | (u1 & 0xffff0000u);
                }
                bf16x8 af = *(bf16x8*)&af_u;
                #pragma unroll
                for (int nt = 0; nt < 4; nt++)
                    hacc[mt*4+nt] = __builtin_amdgcn_mfma_f32_16x16x32_bf16(af, bfr[kq][nt], hacc[mt*4+nt], 0, 0, 0);
            }
        }
        #pragma unroll
        for (int mt = 0; mt < 3; mt++)
            #pragma unroll
            for (int nt = 0; nt < 4; nt++){
                float b2 = rb2s[nt*16 + l15];
                #pragma unroll
                for (int e = 0; e < 4; e++){
                    int row = w*48 + mt*16 + q*4 + e;
                    smH[row*72 + nt*16 + l15] = f2bf_t(sspf_lean(hacc[mt*4+nt][e] + b2));
                }
            }
        #pragma unroll
        for (int kq = 0; kq < 2; kq++){
            bf16x8 af[3];
            #pragma unroll
            for (int mt = 0; mt < 3; mt++)
                af[mt] = *(const bf16x8*)(smH + (w*48 + mt*16 + l15)*72 + kq*32 + q*8);
            #pragma unroll
            for (int nt = 0; nt < 8; nt++){
                bf16x8 bb = *(const bf16x8*)(smB[buf] + (nt*16 + l15)*72 + kq*32 + q*8);
                #pragma unroll
                for (int mt = 0; mt < 3; mt++)
                    acc[mt*8+nt] = __builtin_amdgcn_mfma_f32_16x16x32_bf16(af[mt], bb, acc[mt*8+nt], 0, 0, 0);
            }
        }
    }
    // epilogue: LDS-staged contiguous write of part tile (192x128 bf16)
    unsigned short* stg = smH;               // row stride 136 shorts
    #pragma unroll
    for (int half = 0; half < 2; half++){
        __syncthreads();
        if ((w >> 1) == half){
            int wl = w & 1;
            #pragma unroll
            for (int mt = 0; mt < 3; mt++)
                #pragma unroll
                for (int nt = 0; nt < 8; nt++)
                    #pragma unroll
                    for (int e = 0; e < 4; e++){
                        int row = wl*48 + mt*16 + q*4 + e;      // [0,96)
                        stg[row*136 + nt*16 + l15] = f2bf_t(acc[mt*8+nt][e]);
                    }
        }
        __syncthreads();
        unsigned short* gdst = part + ((size_t)(z*NKC + kc)*NATOMS + half*96)*128;
        #pragma unroll
        for (int it = 0; it < 6; it++){
            int flat = tid + it*256;          // [0,1536) uint4s
            int row = flat >> 4, cc = flat & 15;
            uint4 v = *(const uint4*)(stg + row*136 + cc*8);
            *(uint4*)(gdst + row*128 + cc*8) = v;
        }
    }
}

// ---------------- reduce partials + sp + mask -> bf16 next features (layer 0 only)
__global__ void k_reduceB(const unsigned short* __restrict__ part, const float* __restrict__ mask,
                          unsigned short* __restrict__ fb, unsigned short* __restrict__ fc){
    int zl = blockIdx.y;
    int idx = blockIdx.x*256 + threadIdx.x;    // [0, 24576)
    int a = idx >> 7, j2 = idx & 127;
    const unsigned short* p = part + ((size_t)(zl*NKC)*NATOMS + a)*128 + j2;
    float s = 0.f;
    #pragma unroll
    for (int c = 0; c < NKC; c++) s += bf2f(p[(size_t)c*NATOMS*128]);
    int rowg = zl*NATOMS + a;
    float v = spf_act(s) * mask[rowg];
    if (j2 < 64) fb[rowg*64 + j2] = f2bf(v);
    else         fc[rowg*64 + j2 - 64] = f2bf(v);
}

// ---------------- fused tail: reduce(layer1) + sp + mask + h1 + BN1 + leaky + h2 + BN2
// + leaky + mask + atom-sum (atomicAdd into zeroed out). One block per atom.
__global__ __launch_bounds__(256) void k_head2(
    const unsigned short* __restrict__ part, const float* __restrict__ mask,
    const float* __restrict__ fW1, const float* __restrict__ fb1,
    const float* __restrict__ fW2, const float* __restrict__ fb2,
    float* __restrict__ out)
{
    __shared__ float X[2048];
    __shared__ float red[16];
    __shared__ float stats[2];
    int a = blockIdx.x, tid = threadIdx.x;
    int lane = tid & 63, w = tid >> 6;

    // reduce part over kc -> features X[z*128 + j2]
    #pragma unroll
    for (int i = 0; i < 8; i++){
        int idx = tid + i*256; int z = idx >> 7, j2 = idx & 127;
        const unsigned short* p = part + ((size_t)(z*NKC)*NATOMS + a)*128 + j2;
        float s = 0.f;
        #pragma unroll
        for (int c = 0; c < NKC; c++) s += bf2f(p[(size_t)c*NATOMS*128]);
        X[idx] = spf_act(s) * mask[z*NATOMS + a];
    }
    __syncthreads();
    // h1
    f32x4 v[2]; float s = 0.f, ss = 0.f;
    #pragma unroll
    for (int i = 0; i < 2; i++){
        int idx4 = tid + i*256; int z = idx4 >> 5, k4 = (idx4 & 31)*4;
        f32x4 acc = { fb1[k4], fb1[k4+1], fb1[k4+2], fb1[k4+3] };
        #pragma unroll 4
        for (int c = 0; c < 128; c++){
            float xv = X[z*128 + c];
            float4 wv = *(const float4*)(fW1 + (size_t)c*128 + k4);
            acc[0] += xv*wv.x; acc[1] += xv*wv.y; acc[2] += xv*wv.z; acc[3] += xv*wv.w;
        }
        v[i] = acc;
        s += acc[0]+acc[1]+acc[2]+acc[3];
        ss += acc[0]*acc[0]+acc[1]*acc[1]+acc[2]*acc[2]+acc[3]*acc[3];
    }
    for (int off = 32; off; off >>= 1){ s += __shfl_down(s, off); ss += __shfl_down(ss, off); }
    if (!lane){ red[w] = s; red[8+w] = ss; }
    __syncthreads();
    if (!tid){
        float S = red[0]+red[1]+red[2]+red[3];
        float SS = red[8]+red[9]+red[10]+red[11];
        float m = S*(1.f/2048.f), var = SS*(1.f/2048.f) - m*m;
        stats[0] = m; stats[1] = rsqrtf(var + 1e-5f);
    }
    __syncthreads();
    float m1 = stats[0], inv1 = stats[1];
    #pragma unroll
    for (int i = 0; i < 2; i++){
        int idx4 = tid + i*256;
        f32x4 t;
        #pragma unroll
        for (int e = 0; e < 4; e++){
            float x = (v[i][e]-m1)*inv1;
            t[e] = (x > 0.f) ? x : 0.2f*x;
        }
        *(f32x4*)(X + idx4*4) = t;
    }
    __syncthreads();
    // h2
    float u[2]; s = 0.f; ss = 0.f;
    #pragma unroll
    for (int i = 0; i < 2; i++){
        int idx = tid + i*256; int z = idx >> 5, j = idx & 31;
        float acc = fb2[j];
        #pragma unroll 8
        for (int k = 0; k < 128; k++) acc += X[z*128 + k]*fW2[k*32 + j];
        u[i] = acc; s += acc; ss += acc*acc;
    }
    for (int off = 32; off; off >>= 1){ s += __shfl_down(s, off); ss += __shfl_down(ss, off); }
    if (!lane){ red[w] = s; red[8+w] = ss; }
    __syncthreads();
    if (!tid){
        float S = red[0]+red[1]+red[2]+red[3];
        float SS = red[8]+red[9]+red[10]+red[11];
        float m = S*(1.f/512.f), var = SS*(1.f/512.f) - m*m;
        stats[0] = m; stats[1] = rsqrtf(var + 1e-5f);
    }
    __syncthreads();
    float m2 = stats[0], inv2 = stats[1];
    #pragma unroll
    for (int i = 0; i < 2; i++){
        int idx = tid + i*256; int z = idx >> 5, j = idx & 31;
        float x = (u[i]-m2)*inv2;
        x = (x > 0.f) ? x : 0.2f*x;
        x *= mask[z*NATOMS + a];
        atomicAdd(&out[z*32 + j], x);
    }
}

extern "C" void kernel_launch(void* const* d_in, const int* in_sizes, int n_in,
                              void* d_out, int out_size, void* d_ws, size_t ws_size,
                              hipStream_t stream){
    const float* features = (const float*)d_in[0];
    const float* geometry = (const float*)d_in[1];
    const float* mask     = (const float*)d_in[2];
    const float* W_bio    = (const float*)d_in[3];
    const float* b_bio    = (const float*)d_in[4];
    const float* W_ch     = (const float*)d_in[5];
    const float* b_ch     = (const float*)d_in[6];
    const float* rW1[2] = {(const float*)d_in[7],  (const float*)d_in[12]};
    const float* rb1[2] = {(const float*)d_in[8],  (const float*)d_in[13]};
    const float* rW2[2] = {(const float*)d_in[9],  (const float*)d_in[14]};
    const float* rb2[2] = {(const float*)d_in[10], (const float*)d_in[15]};
    const float* rWo[2] = {(const float*)d_in[11], (const float*)d_in[16]};
    const float* fW1 = (const float*)d_in[17];
    const float* fb1 = (const float*)d_in[18];
    const float* fW2 = (const float*)d_in[19];
    const float* fb2 = (const float*)d_in[20];

    char* ws = (char*)d_ws;
    unsigned short* fAb = (unsigned short*)ws;   ws += (size_t)ZA*64*2;
    unsigned short* fAc = (unsigned short*)ws;   ws += (size_t)ZA*64*2;
    unsigned short* w2T = (unsigned short*)ws;   ws += (size_t)2*4096*2;
    unsigned short* Bp = (unsigned short*)ws;    ws += (size_t)2*262144*2;           // 1 MB
    unsigned short* Tg = (unsigned short*)ws;    ws += (size_t)ZA*8192*2;            // 50.3 MB
    unsigned short* part = (unsigned short*)ws;  ws += (size_t)ZB*NKC*NATOMS*128*2;   // 25.2 MB

    hipMemsetAsync(d_out, 0, (size_t)out_size*sizeof(float), stream);

    dim3 gt(24, 32, 2);
    dim3 gf(ZB, NKC);
    dim3 gd(96, ZB);
    // one prep launch: both layers' w2T + Bp
    k_prep<<<512, 256, 0, stream>>>(rW2[0], rW2[1], rWo[0], rWo[1], w2T, Bp);
    // layer 0 (encode fused into tmpB)
    k_tmpB<<<gt, 256, 0, stream>>>(nullptr, nullptr, features, W_bio, b_bio, W_ch, b_ch,
                                   mask, Bp, Tg);
    k_fused<<<gf, 256, 0, stream>>>(geometry, rW1[0], rb1[0], w2T, rb2[0], Tg, part);
    k_reduceB<<<gd, 256, 0, stream>>>(part, mask, fAb, fAc);
    // layer 1
    k_tmpB<<<gt, 256, 0, stream>>>(fAb, fAc, nullptr, W_bio, b_bio, W_ch, b_ch,
                                   mask, Bp + 262144, Tg);
    k_fused<<<gf, 256, 0, stream>>>(geometry, rW1[1], rb1[1], w2T + 4096, rb2[1], Tg, part);
    // fused tail: reduce(layer1) + head + sum (atomics into zeroed out)
    k_head2<<<NATOMS, 256, 0, stream>>>(part, mask, fW1, fb1, fW2, fb2, (float*)d_out);
}